// Round 1
// baseline (253.987 us; speedup 1.0000x reference)
//
#include <hip/hip_runtime.h>
#include <cstdint>

#define NROWS 50000
#define NCLS  91
#define KPRE  1000
#define NDET  100
#define HIST_BINS 65536
#define BIN_SHIFT 14
#define CAP   4096
#define LOGCLAMP 4.135166556742356f

// ---- workspace layout (bytes) ----
constexpr size_t OFF_HIST    = 0;                         // 65536*4 = 262144
constexpr size_t OFF_CNT     = 262144;                    // 64 B: [0]=cutoff bin, [1]=compact count
constexpr size_t OFF_COMPACT = OFF_CNT + 64;              // CAP*8 = 32768
constexpr size_t OFF_SSCORE  = OFF_COMPACT + CAP * 8;     // 1024*4
constexpr size_t OFF_SGIDX   = OFF_SSCORE + 4096;         // 1024*4
constexpr size_t OFF_SLABEL  = OFF_SGIDX + 4096;          // 1024*4
constexpr size_t OFF_BRAW    = OFF_SLABEL + 4096;         // 1000*16 -> pad 16384
constexpr size_t OFF_BNMS    = OFF_BRAW + 16384;          // 16384
constexpr size_t OFF_MASK    = OFF_BNMS + 16384;          // 1000*16*8 = 128000

__device__ __forceinline__ bool decode_box(int row, int c,
    const float* __restrict__ regr, const float* __restrict__ props,
    float W, float H, float4& b) {
  const float4 rr = *reinterpret_cast<const float4*>(regr + (size_t)row * (NCLS * 4) + c * 4);
  const float4 pp = *reinterpret_cast<const float4*>(props + (size_t)row * 4);
  float pw = pp.z - pp.x, ph = pp.w - pp.y;
  float cx = pp.x + 0.5f * pw, cy = pp.y + 0.5f * ph;
  float dx = rr.x / 10.0f, dy = rr.y / 10.0f;
  float dw = fminf(rr.z / 5.0f, LOGCLAMP);
  float dh = fminf(rr.w / 5.0f, LOGCLAMP);
  float pcx = dx * pw + cx, pcy = dy * ph + cy;
  float ppw = expf(dw) * pw, pph = expf(dh) * ph;
  float x1 = fminf(fmaxf(pcx - 0.5f * ppw, 0.f), W);
  float y1 = fminf(fmaxf(pcy - 0.5f * pph, 0.f), H);
  float x2 = fminf(fmaxf(pcx + 0.5f * ppw, 0.f), W);
  float y2 = fminf(fmaxf(pcy + 0.5f * pph, 0.f), H);
  b = make_float4(x1, y1, x2, y2);
  return (x2 - x1 >= 0.01f) && (y2 - y1 >= 0.01f);
}

// MODE 0: histogram valid candidate scores.  MODE 1: compact candidates >= cutoff bin.
template <int MODE>
__global__ __launch_bounds__(256)
void cand_kernel(const float* __restrict__ logits,
                 const float* __restrict__ regr,
                 const float* __restrict__ props,
                 const int* __restrict__ p_imh,
                 const int* __restrict__ p_imw,
                 uint32_t* __restrict__ hist,
                 uint32_t* __restrict__ cnt,
                 unsigned long long* __restrict__ compact) {
  const int lane = threadIdx.x & 63;
  const int row  = blockIdx.x * 4 + (threadIdx.x >> 6);
  if (row >= NROWS) return;

  const float* lr = logits + (size_t)row * NCLS;
  float x0 = (lane < NCLS)      ? lr[lane]      : -INFINITY;
  float x1 = (lane + 64 < NCLS) ? lr[lane + 64] : -INFINITY;
  float m = fmaxf(x0, x1);
  #pragma unroll
  for (int o = 32; o; o >>= 1) m = fmaxf(m, __shfl_xor(m, o));
  float e0 = (lane < NCLS)      ? expf(x0 - m) : 0.f;
  float e1 = (lane + 64 < NCLS) ? expf(x1 - m) : 0.f;
  float s = e0 + e1;
  #pragma unroll
  for (int o = 32; o; o >>= 1) s += __shfl_xor(s, o);

  const float W = (float)(*p_imw), H = (float)(*p_imh);
  const uint32_t cut = (MODE == 1) ? cnt[0] : 0u;

  #pragma unroll
  for (int half = 0; half < 2; ++half) {
    int c = lane + half * 64;
    float e = half ? e1 : e0;
    if (c >= 1 && c < NCLS) {
      float score = e / s;
      if (score > 0.05f) {
        float4 b;
        if (decode_box(row, c, regr, props, W, H, b)) {
          uint32_t bits = __float_as_uint(score);
          uint32_t bin = bits >> BIN_SHIFT;
          if (MODE == 0) {
            atomicAdd(&hist[bin], 1u);
          } else if (bin >= cut) {
            uint32_t pos = atomicAdd(&cnt[1], 1u);
            if (pos < CAP) {
              uint32_t gidx = (uint32_t)row * 90u + (uint32_t)(c - 1);
              compact[pos] = ((unsigned long long)bits << 32) |
                             (unsigned long long)(0xFFFFFFFFu - gidx);
            }
          }
        }
      }
    }
  }
}

__global__ __launch_bounds__(1024)
void cutoff_kernel(const uint32_t* __restrict__ hist, uint32_t* __restrict__ cnt) {
  __shared__ uint32_t sh[1024];
  const int t = threadIdx.x;
  uint32_t s = 0;
  for (int i = 0; i < 64; ++i) s += hist[t * 64 + i];
  sh[t] = s;
  __syncthreads();
  uint32_t v = s;
  for (int off = 1; off < 1024; off <<= 1) {
    uint32_t add = (t + off < 1024) ? sh[t + off] : 0;
    __syncthreads();
    v += add;
    sh[t] = v;
    __syncthreads();
  }
  const uint32_t total = sh[0];
  if (total == 0) { if (t == 0) cnt[0] = 0xFFFFFFFFu; return; }
  const uint32_t target = total < (uint32_t)KPRE ? total : (uint32_t)KPRE;
  const uint32_t rs_t = sh[t];
  const uint32_t rs_n = (t < 1023) ? sh[t + 1] : 0;
  if (rs_t >= target && rs_n < target) {
    uint32_t acc = rs_n;
    for (int b = 63; b >= 0; --b) {
      acc += hist[t * 64 + b];
      if (acc >= target) { cnt[0] = (uint32_t)(t * 64 + b); break; }
    }
  }
}

__global__ __launch_bounds__(1024)
void sort_kernel(const unsigned long long* __restrict__ compact,
                 const uint32_t* __restrict__ cnt,
                 float* __restrict__ sel_score, uint32_t* __restrict__ sel_gidx) {
  __shared__ unsigned long long arr[CAP];
  const int t = threadIdx.x;
  const uint32_t M = cnt[1] < (uint32_t)CAP ? cnt[1] : (uint32_t)CAP;
  for (int i = t; i < CAP; i += 1024) arr[i] = (i < (int)M) ? compact[i] : 0ull;
  __syncthreads();
  for (int k = 2; k <= CAP; k <<= 1) {
    for (int j = k >> 1; j > 0; j >>= 1) {
      for (int i = t; i < CAP; i += 1024) {
        int l = i ^ j;
        if (l > i) {
          unsigned long long A = arr[i], B = arr[l];
          bool up = ((i & k) == 0);
          if (up ? (A > B) : (A < B)) { arr[i] = B; arr[l] = A; }
        }
      }
      __syncthreads();
    }
  }
  if (t < KPRE) {
    unsigned long long e = arr[CAP - 1 - t];   // descending order
    if (e) {
      sel_score[t] = __uint_as_float((uint32_t)(e >> 32));
      sel_gidx[t]  = 0xFFFFFFFFu - (uint32_t)e;
    } else {
      sel_score[t] = -1.f;
      sel_gidx[t]  = 0xFFFFFFFFu;
    }
  }
}

__global__ __launch_bounds__(1024)
void prep_kernel(const float* __restrict__ regr, const float* __restrict__ props,
                 const int* __restrict__ p_imh, const int* __restrict__ p_imw,
                 const float* __restrict__ sel_score, const uint32_t* __restrict__ sel_gidx,
                 int* __restrict__ slabel, float4* __restrict__ braw,
                 float4* __restrict__ bnms) {
  const int t = threadIdx.x;
  if (t >= KPRE) return;
  float sc = sel_score[t];
  if (sc > 0.f) {
    uint32_t g = sel_gidx[t];
    int row = (int)(g / 90u);
    int c   = (int)(g % 90u) + 1;
    float W = (float)(*p_imw), H = (float)(*p_imh);
    float4 b;
    decode_box(row, c, regr, props, W, H, b);
    braw[t] = b;
    float off = (float)c * (float)(*p_imw + *p_imh + 2);
    bnms[t] = make_float4(b.x + off, b.y + off, b.z + off, b.w + off);
    slabel[t] = c;
  } else {
    braw[t] = make_float4(0, 0, 0, 0);
    bnms[t] = make_float4(0, 0, 0, 0);
    slabel[t] = 0;
  }
}

__global__ __launch_bounds__(64)
void iou_kernel(const float4* __restrict__ bnms, unsigned long long* __restrict__ mask) {
  const int i = blockIdx.x;
  const int lane = threadIdx.x;
  const float4 bi = bnms[i];
  const float areai = fmaxf(bi.z - bi.x, 0.f) * fmaxf(bi.w - bi.y, 0.f);
  #pragma unroll
  for (int w = 0; w < 16; ++w) {
    int j = w * 64 + lane;
    bool bit = false;
    if (j < KPRE && j > i) {
      float4 bj = bnms[j];
      float areaj = fmaxf(bj.z - bj.x, 0.f) * fmaxf(bj.w - bj.y, 0.f);
      float ltx = fmaxf(bi.x, bj.x), lty = fmaxf(bi.y, bj.y);
      float rbx = fminf(bi.z, bj.z), rby = fminf(bi.w, bj.w);
      float iw = fmaxf(rbx - ltx, 0.f), ih = fmaxf(rby - lty, 0.f);
      float inter = iw * ih;
      float iou = inter / (areai + areaj - inter + 1e-7f);
      bit = iou > 0.5f;
    }
    unsigned long long mword = __ballot(bit);
    if (lane == 0) mask[(size_t)i * 16 + w] = mword;
  }
}

__global__ __launch_bounds__(64)
void greedy_kernel(const unsigned long long* __restrict__ mask,
                   const float* __restrict__ sel_score,
                   const int* __restrict__ slabel,
                   const float4* __restrict__ braw,
                   float* __restrict__ out) {
  const int lane = threadIdx.x;
  // build keep0 bitset: lanes 0..15 each hold one 64-bit word
  unsigned long long kw = 0ull;
  #pragma unroll
  for (int w = 0; w < 16; ++w) {
    int j = w * 64 + lane;
    bool b = (j < KPRE) && (sel_score[j] > 0.f);
    unsigned long long mword = __ballot(b);
    if (lane == w) kw = mword;
  }
  __shared__ int kept[NDET];
  int kc = 0;
  for (int i = 0; i < KPRE && kc < NDET; ++i) {
    unsigned long long mrow = (lane < 16) ? mask[(size_t)i * 16 + lane] : 0ull;
    unsigned long long kwv = __shfl(kw, i >> 6);
    if ((kwv >> (i & 63)) & 1ull) {
      kw &= ~mrow;
      if (lane == 0) kept[kc] = i;
      ++kc;
    }
  }
  __syncthreads();
  for (int t = lane; t < NDET; t += 64) {
    if (t < kc) {
      int i = kept[t];
      float4 b = braw[i];
      out[t * 4 + 0] = b.x; out[t * 4 + 1] = b.y;
      out[t * 4 + 2] = b.z; out[t * 4 + 3] = b.w;
      out[4 * NDET + t] = sel_score[i];
      out[5 * NDET + t] = (float)slabel[i];
    } else {
      out[t * 4 + 0] = 0.f; out[t * 4 + 1] = 0.f;
      out[t * 4 + 2] = 0.f; out[t * 4 + 3] = 0.f;
      out[4 * NDET + t] = 0.f;
      out[5 * NDET + t] = 0.f;
    }
  }
}

extern "C" void kernel_launch(void* const* d_in, const int* in_sizes, int n_in,
                              void* d_out, int out_size, void* d_ws, size_t ws_size,
                              hipStream_t stream) {
  const float* logits = (const float*)d_in[0];
  const float* regr   = (const float*)d_in[1];
  const float* props  = (const float*)d_in[2];
  const int*   p_imh  = (const int*)d_in[3];
  const int*   p_imw  = (const int*)d_in[4];
  float* out = (float*)d_out;

  uint8_t* ws = (uint8_t*)d_ws;
  uint32_t* hist = (uint32_t*)(ws + OFF_HIST);
  uint32_t* cnt  = (uint32_t*)(ws + OFF_CNT);
  unsigned long long* compact = (unsigned long long*)(ws + OFF_COMPACT);
  float*    sel_score = (float*)(ws + OFF_SSCORE);
  uint32_t* sel_gidx  = (uint32_t*)(ws + OFF_SGIDX);
  int*      slabel    = (int*)(ws + OFF_SLABEL);
  float4*   braw      = (float4*)(ws + OFF_BRAW);
  float4*   bnms      = (float4*)(ws + OFF_BNMS);
  unsigned long long* mask = (unsigned long long*)(ws + OFF_MASK);

  // zero histogram + counters (harness does not re-poison between replays)
  hipMemsetAsync(ws, 0, OFF_CNT + 64, stream);

  dim3 grid((NROWS + 3) / 4);
  cand_kernel<0><<<grid, 256, 0, stream>>>(logits, regr, props, p_imh, p_imw,
                                           hist, cnt, compact);
  cutoff_kernel<<<1, 1024, 0, stream>>>(hist, cnt);
  cand_kernel<1><<<grid, 256, 0, stream>>>(logits, regr, props, p_imh, p_imw,
                                           hist, cnt, compact);
  sort_kernel<<<1, 1024, 0, stream>>>(compact, cnt, sel_score, sel_gidx);
  prep_kernel<<<1, 1024, 0, stream>>>(regr, props, p_imh, p_imw,
                                      sel_score, sel_gidx, slabel, braw, bnms);
  iou_kernel<<<KPRE, 64, 0, stream>>>(bnms, mask);
  greedy_kernel<<<1, 64, 0, stream>>>(mask, sel_score, slabel, braw, out);
}

// Round 2
// 206.122 us; speedup vs baseline: 1.2322x; 1.2322x over previous
//
#include <hip/hip_runtime.h>
#include <cstdint>

#define NROWS 50000
#define NCLS  91
#define KPRE  1000
#define NDET  100
#define CAP   4096
#define RPB   64            // rows per block in pass1
#define HBINS 4096
#define BIN_BASE 61440u     // (bits>>14) offset; scores in (0.05,1] -> bins [1331,3583]
#define LOGCLAMP 4.135166556742356f

// ---- workspace layout (bytes) ----
constexpr size_t OFF_HIST    = 0;                          // 4096*4 = 16384
constexpr size_t OFF_CNT     = 16384;                      // 64 B: [0]=cutoff bin, [1]=compact count
constexpr size_t OFF_ROWMAX  = OFF_CNT + 64;               // 50000*2 -> pad 100032
constexpr size_t OFF_COMPACT = OFF_ROWMAX + 100032;        // CAP*8 = 32768
constexpr size_t OFF_SSCORE  = OFF_COMPACT + CAP * 8;      // 1024*4
constexpr size_t OFF_SGIDX   = OFF_SSCORE + 4096;          // 1024*4
constexpr size_t OFF_SLABEL  = OFF_SGIDX + 4096;           // 1024*4
constexpr size_t OFF_BRAW    = OFF_SLABEL + 4096;          // 16384
constexpr size_t OFF_BNMS    = OFF_BRAW + 16384;           // 16384
constexpr size_t OFF_MASK    = OFF_BNMS + 16384;           // 1000*16*8 = 128000

__device__ __forceinline__ bool decode_box(int row, int c,
    const float* __restrict__ regr, const float* __restrict__ props,
    float W, float H, float4& b) {
  const float4 rr = *reinterpret_cast<const float4*>(regr + (size_t)row * (NCLS * 4) + c * 4);
  const float4 pp = *reinterpret_cast<const float4*>(props + (size_t)row * 4);
  float pw = pp.z - pp.x, ph = pp.w - pp.y;
  float cx = pp.x + 0.5f * pw, cy = pp.y + 0.5f * ph;
  float dx = rr.x / 10.0f, dy = rr.y / 10.0f;
  float dw = fminf(rr.z / 5.0f, LOGCLAMP);
  float dh = fminf(rr.w / 5.0f, LOGCLAMP);
  float pcx = dx * pw + cx, pcy = dy * ph + cy;
  float ppw = expf(dw) * pw, pph = expf(dh) * ph;
  float x1 = fminf(fmaxf(pcx - 0.5f * ppw, 0.f), W);
  float y1 = fminf(fmaxf(pcy - 0.5f * pph, 0.f), H);
  float x2 = fminf(fmaxf(pcx + 0.5f * ppw, 0.f), W);
  float y2 = fminf(fmaxf(pcy + 0.5f * pph, 0.f), H);
  b = make_float4(x1, y1, x2, y2);
  return (x2 - x1 >= 0.01f) && (y2 - y1 >= 0.01f);
}

// Pass 1: LDS-staged softmax; 4 threads/row, 23 classes/thread.
// Histograms valid candidates, records per-row max valid bin.
__global__ __launch_bounds__(256)
void pass1_kernel(const float* __restrict__ logits,
                  const float* __restrict__ regr,
                  const float* __restrict__ props,
                  const int* __restrict__ p_imh,
                  const int* __restrict__ p_imw,
                  uint32_t* __restrict__ hist,
                  uint16_t* __restrict__ rowmax) {
  __shared__ float lds[RPB * NCLS];
  const int t = threadIdx.x;
  const int r0 = blockIdx.x * RPB;
  const size_t base = (size_t)r0 * NCLS;
  const size_t nfl = (size_t)NROWS * NCLS;           // 4550000, divisible by 4
  size_t rend = base + (size_t)RPB * NCLS; if (rend > nfl) rend = nfl;
  const size_t s4 = base >> 2;
  const size_t e4 = (rend + 3) >> 2;
  const int off = (int)(base - s4 * 4);
  for (size_t i4 = s4 + t; i4 < e4; i4 += 256) {
    float4 v = *reinterpret_cast<const float4*>(logits + i4 * 4);
    int p = (int)((i4 - s4) * 4) - off;
    const float* vv = reinterpret_cast<const float*>(&v);
    #pragma unroll
    for (int k = 0; k < 4; ++k) {
      int q = p + k;
      if (q >= 0 && q < RPB * NCLS) lds[q] = vv[k];
    }
  }
  __syncthreads();

  const int row = r0 + (t >> 2);
  const int sub = t & 3;
  if (row >= NROWS) return;
  const float W = (float)(*p_imw), H = (float)(*p_imh);
  const float* ls = &lds[(t >> 2) * NCLS];

  float x[23];
  #pragma unroll
  for (int j = 0; j < 23; ++j) {
    int c = sub + 4 * j;
    x[j] = (c < NCLS) ? ls[c] : -INFINITY;
  }
  float m = x[0];
  #pragma unroll
  for (int j = 1; j < 23; ++j) m = fmaxf(m, x[j]);
  m = fmaxf(m, __shfl_xor(m, 1));
  m = fmaxf(m, __shfl_xor(m, 2));
  float e[23]; float s = 0.f;
  #pragma unroll
  for (int j = 0; j < 23; ++j) {
    e[j] = (sub + 4 * j < NCLS) ? expf(x[j] - m) : 0.f;
    s += e[j];
  }
  s += __shfl_xor(s, 1);
  s += __shfl_xor(s, 2);

  int maxbin = 0;
  #pragma unroll
  for (int j = 0; j < 23; ++j) {
    int c = sub + 4 * j;
    if (c >= 1 && c < NCLS) {
      float score = e[j] / s;
      if (score > 0.05f) {
        float4 b;
        if (decode_box(row, c, regr, props, W, H, b)) {
          uint32_t bin = (__float_as_uint(score) >> 14) - BIN_BASE;
          atomicAdd(&hist[bin], 1u);
          if ((int)bin > maxbin) maxbin = (int)bin;
        }
      }
    }
  }
  maxbin = max(maxbin, __shfl_xor(maxbin, 1));
  maxbin = max(maxbin, __shfl_xor(maxbin, 2));
  if (sub == 0) rowmax[row] = (uint16_t)maxbin;
}

__global__ __launch_bounds__(256)
void cutoff_kernel(const uint32_t* __restrict__ hist, uint32_t* __restrict__ cnt) {
  __shared__ uint32_t sh[256];
  const int t = threadIdx.x;
  uint32_t s = 0;
  for (int i = 0; i < 16; ++i) s += hist[t * 16 + i];
  sh[t] = s;
  __syncthreads();
  uint32_t v = s;
  for (int offn = 1; offn < 256; offn <<= 1) {
    uint32_t add = (t + offn < 256) ? sh[t + offn] : 0;
    __syncthreads();
    v += add;
    sh[t] = v;
    __syncthreads();
  }
  const uint32_t total = sh[0];
  if (total == 0) { if (t == 0) cnt[0] = 0xFFFFFFFFu; return; }
  const uint32_t target = total < (uint32_t)KPRE ? total : (uint32_t)KPRE;
  const uint32_t rs_t = sh[t];
  const uint32_t rs_n = (t < 255) ? sh[t + 1] : 0;
  if (rs_t >= target && rs_n < target) {
    uint32_t acc = rs_n;
    for (int b = 15; b >= 0; --b) {
      acc += hist[t * 16 + b];
      if (acc >= target) { cnt[0] = (uint32_t)(t * 16 + b); break; }
    }
  }
}

// Refine: only rows whose max valid bin >= cutoff get re-processed.
// Arithmetic replicates pass1 op-for-op (serial-23 max/sum + shfl 1,2).
__global__ __launch_bounds__(256)
void refine_kernel(const float* __restrict__ logits,
                   const float* __restrict__ regr,
                   const float* __restrict__ props,
                   const int* __restrict__ p_imh,
                   const int* __restrict__ p_imw,
                   const uint16_t* __restrict__ rowmax,
                   uint32_t* __restrict__ cnt,
                   unsigned long long* __restrict__ compact) {
  const int t = threadIdx.x;
  const int lane = t & 63;
  const uint32_t cut = cnt[0];
  const int myrow = blockIdx.x * 256 + t;
  bool qual = (myrow < NROWS) && ((uint32_t)rowmax[myrow] >= cut);
  unsigned long long bm = __ballot(qual);
  if (!bm) return;
  const int waveBase = blockIdx.x * 256 + (t & ~63);
  const float W = (float)(*p_imw), H = (float)(*p_imh);
  const int sub = lane & 3;

  while (bm) {
    int b = __ffsll((unsigned long long)bm) - 1;
    bm &= bm - 1;
    int row = waveBase + b;
    const float* lr = logits + (size_t)row * NCLS;
    float x[23];
    #pragma unroll
    for (int j = 0; j < 23; ++j) {
      int c = sub + 4 * j;
      x[j] = (c < NCLS) ? lr[c] : -INFINITY;
    }
    float m = x[0];
    #pragma unroll
    for (int j = 1; j < 23; ++j) m = fmaxf(m, x[j]);
    m = fmaxf(m, __shfl_xor(m, 1));
    m = fmaxf(m, __shfl_xor(m, 2));
    float e[23]; float s = 0.f;
    #pragma unroll
    for (int j = 0; j < 23; ++j) {
      e[j] = (sub + 4 * j < NCLS) ? expf(x[j] - m) : 0.f;
      s += e[j];
    }
    s += __shfl_xor(s, 1);
    s += __shfl_xor(s, 2);
    if (lane < 4) {
      #pragma unroll
      for (int j = 0; j < 23; ++j) {
        int c = sub + 4 * j;
        if (c >= 1 && c < NCLS) {
          float score = e[j] / s;
          if (score > 0.05f) {
            float4 bb;
            if (decode_box(row, c, regr, props, W, H, bb)) {
              uint32_t bits = __float_as_uint(score);
              uint32_t bin = (bits >> 14) - BIN_BASE;
              if (bin >= cut) {
                uint32_t pos = atomicAdd(&cnt[1], 1u);
                if (pos < CAP) {
                  uint32_t gidx = (uint32_t)row * 90u + (uint32_t)(c - 1);
                  compact[pos] = ((unsigned long long)bits << 32) |
                                 (unsigned long long)(0xFFFFFFFFu - gidx);
                }
              }
            }
          }
        }
      }
    }
  }
}

// Bitonic sort (width = next pow2 >= count, >=1024) + fold in prep (decode selected).
__global__ __launch_bounds__(1024)
void sort_prep_kernel(const unsigned long long* __restrict__ compact,
                      const uint32_t* __restrict__ cnt,
                      const float* __restrict__ regr, const float* __restrict__ props,
                      const int* __restrict__ p_imh, const int* __restrict__ p_imw,
                      float* __restrict__ sel_score, uint32_t* __restrict__ sel_gidx,
                      int* __restrict__ slabel, float4* __restrict__ braw,
                      float4* __restrict__ bnms) {
  __shared__ unsigned long long arr[CAP];
  const int t = threadIdx.x;
  const uint32_t M = cnt[1] < (uint32_t)CAP ? cnt[1] : (uint32_t)CAP;
  int P = 1024;
  while (P < (int)M) P <<= 1;
  for (int i = t; i < P; i += 1024) arr[i] = (i < (int)M) ? compact[i] : 0ull;
  __syncthreads();
  for (int k = 2; k <= P; k <<= 1) {
    for (int j = k >> 1; j > 0; j >>= 1) {
      for (int i = t; i < P; i += 1024) {
        int l = i ^ j;
        if (l > i) {
          unsigned long long A = arr[i], B = arr[l];
          bool up = ((i & k) == 0);
          if (up ? (A > B) : (A < B)) { arr[i] = B; arr[l] = A; }
        }
      }
      __syncthreads();
    }
  }
  if (t < KPRE) {
    unsigned long long en = arr[P - 1 - t];   // descending
    float sc; uint32_t g;
    if (en) { sc = __uint_as_float((uint32_t)(en >> 32)); g = 0xFFFFFFFFu - (uint32_t)en; }
    else    { sc = -1.f; g = 0xFFFFFFFFu; }
    sel_score[t] = sc;
    sel_gidx[t] = g;
    if (sc > 0.f) {
      int row = (int)(g / 90u);
      int c   = (int)(g % 90u) + 1;
      float W = (float)(*p_imw), H = (float)(*p_imh);
      float4 b;
      decode_box(row, c, regr, props, W, H, b);
      braw[t] = b;
      float offv = (float)c * (float)(*p_imw + *p_imh + 2);
      bnms[t] = make_float4(b.x + offv, b.y + offv, b.z + offv, b.w + offv);
      slabel[t] = c;
    } else {
      braw[t] = make_float4(0, 0, 0, 0);
      bnms[t] = make_float4(0, 0, 0, 0);
      slabel[t] = 0;
    }
  }
}

__global__ __launch_bounds__(64)
void iou_kernel(const float4* __restrict__ bnms, unsigned long long* __restrict__ mask) {
  const int i = blockIdx.x;
  const int lane = threadIdx.x;
  const float4 bi = bnms[i];
  const float areai = fmaxf(bi.z - bi.x, 0.f) * fmaxf(bi.w - bi.y, 0.f);
  #pragma unroll
  for (int w = 0; w < 16; ++w) {
    int j = w * 64 + lane;
    bool bit = false;
    if (j < KPRE && j > i) {
      float4 bj = bnms[j];
      float areaj = fmaxf(bj.z - bj.x, 0.f) * fmaxf(bj.w - bj.y, 0.f);
      float ltx = fmaxf(bi.x, bj.x), lty = fmaxf(bi.y, bj.y);
      float rbx = fminf(bi.z, bj.z), rby = fminf(bi.w, bj.w);
      float iw = fmaxf(rbx - ltx, 0.f), ih = fmaxf(rby - lty, 0.f);
      float inter = iw * ih;
      float iou = inter / (areai + areaj - inter + 1e-7f);
      bit = iou > 0.5f;
    }
    unsigned long long mword = __ballot(bit);
    if (lane == 0) mask[(size_t)i * 16 + w] = mword;
  }
}

__global__ __launch_bounds__(64)
void greedy_kernel(const unsigned long long* __restrict__ mask,
                   const float* __restrict__ sel_score,
                   const int* __restrict__ slabel,
                   const float4* __restrict__ braw,
                   float* __restrict__ out) {
  const int lane = threadIdx.x;
  unsigned long long kw = 0ull;
  #pragma unroll
  for (int w = 0; w < 16; ++w) {
    int j = w * 64 + lane;
    bool b = (j < KPRE) && (sel_score[j] > 0.f);
    unsigned long long mword = __ballot(b);
    if (lane == w) kw = mword;
  }
  __shared__ int kept[NDET];
  int kc = 0;
  for (int base = 0; base < KPRE && kc < NDET; base += 8) {
    unsigned long long r0, r1, r2, r3, r4, r5, r6, r7;
    r0 = (lane < 16) ? mask[(size_t)(base + 0) * 16 + lane] : 0ull;
    r1 = (lane < 16) ? mask[(size_t)(base + 1) * 16 + lane] : 0ull;
    r2 = (lane < 16) ? mask[(size_t)(base + 2) * 16 + lane] : 0ull;
    r3 = (lane < 16) ? mask[(size_t)(base + 3) * 16 + lane] : 0ull;
    r4 = (lane < 16) ? mask[(size_t)(base + 4) * 16 + lane] : 0ull;
    r5 = (lane < 16) ? mask[(size_t)(base + 5) * 16 + lane] : 0ull;
    r6 = (lane < 16) ? mask[(size_t)(base + 6) * 16 + lane] : 0ull;
    r7 = (lane < 16) ? mask[(size_t)(base + 7) * 16 + lane] : 0ull;
    #pragma unroll
    for (int u = 0; u < 8; ++u) {
      unsigned long long ru = (u == 0) ? r0 : (u == 1) ? r1 : (u == 2) ? r2 :
                              (u == 3) ? r3 : (u == 4) ? r4 : (u == 5) ? r5 :
                              (u == 6) ? r6 : r7;
      int i = base + u;
      if (kc < NDET) {
        unsigned long long kwv = __shfl(kw, i >> 6);
        if ((kwv >> (i & 63)) & 1ull) {
          kw &= ~ru;
          if (lane == 0) kept[kc] = i;
          ++kc;
        }
      }
    }
  }
  __syncthreads();
  for (int t = lane; t < NDET; t += 64) {
    if (t < kc) {
      int i = kept[t];
      float4 b = braw[i];
      out[t * 4 + 0] = b.x; out[t * 4 + 1] = b.y;
      out[t * 4 + 2] = b.z; out[t * 4 + 3] = b.w;
      out[4 * NDET + t] = sel_score[i];
      out[5 * NDET + t] = (float)slabel[i];
    } else {
      out[t * 4 + 0] = 0.f; out[t * 4 + 1] = 0.f;
      out[t * 4 + 2] = 0.f; out[t * 4 + 3] = 0.f;
      out[4 * NDET + t] = 0.f;
      out[5 * NDET + t] = 0.f;
    }
  }
}

extern "C" void kernel_launch(void* const* d_in, const int* in_sizes, int n_in,
                              void* d_out, int out_size, void* d_ws, size_t ws_size,
                              hipStream_t stream) {
  const float* logits = (const float*)d_in[0];
  const float* regr   = (const float*)d_in[1];
  const float* props  = (const float*)d_in[2];
  const int*   p_imh  = (const int*)d_in[3];
  const int*   p_imw  = (const int*)d_in[4];
  float* out = (float*)d_out;

  uint8_t* ws = (uint8_t*)d_ws;
  uint32_t* hist = (uint32_t*)(ws + OFF_HIST);
  uint32_t* cnt  = (uint32_t*)(ws + OFF_CNT);
  uint16_t* rowmax = (uint16_t*)(ws + OFF_ROWMAX);
  unsigned long long* compact = (unsigned long long*)(ws + OFF_COMPACT);
  float*    sel_score = (float*)(ws + OFF_SSCORE);
  uint32_t* sel_gidx  = (uint32_t*)(ws + OFF_SGIDX);
  int*      slabel    = (int*)(ws + OFF_SLABEL);
  float4*   braw      = (float4*)(ws + OFF_BRAW);
  float4*   bnms      = (float4*)(ws + OFF_BNMS);
  unsigned long long* mask = (unsigned long long*)(ws + OFF_MASK);

  // zero histogram + counters every call (graph replays don't re-poison)
  hipMemsetAsync(ws, 0, OFF_CNT + 64, stream);

  pass1_kernel<<<(NROWS + RPB - 1) / RPB, 256, 0, stream>>>(
      logits, regr, props, p_imh, p_imw, hist, rowmax);
  cutoff_kernel<<<1, 256, 0, stream>>>(hist, cnt);
  refine_kernel<<<(NROWS + 255) / 256, 256, 0, stream>>>(
      logits, regr, props, p_imh, p_imw, rowmax, cnt, compact);
  sort_prep_kernel<<<1, 1024, 0, stream>>>(compact, cnt, regr, props, p_imh, p_imw,
                                           sel_score, sel_gidx, slabel, braw, bnms);
  iou_kernel<<<KPRE, 64, 0, stream>>>(bnms, mask);
  greedy_kernel<<<1, 64, 0, stream>>>(mask, sel_score, slabel, braw, out);
}

// Round 3
// 190.050 us; speedup vs baseline: 1.3364x; 1.0846x over previous
//
#include <hip/hip_runtime.h>
#include <cstdint>

#define NROWS 50000
#define NCLS  91
#define KPRE  1000
#define NDET  100
#define CAP   4096
#define HBINS 4096
#define BIN_BASE 61440u     // (bits>>14)-BIN_BASE; scores (0.05,1] -> bins [1331,3585]
#define LOGCLAMP 4.135166556742356f

// ---- workspace layout (bytes) ----
constexpr size_t OFF_HIST    = 0;                          // 4096*4 = 16384
constexpr size_t OFF_CNT     = 16384;                      // 64 B: [0]=cutoff bin, [1]=compact count
constexpr size_t OFF_ROWMAX  = OFF_CNT + 64;               // 50000*2 -> pad 100032
constexpr size_t OFF_COMPACT = OFF_ROWMAX + 100032;        // CAP*8 = 32768
constexpr size_t OFF_SSCORE  = OFF_COMPACT + CAP * 8;      // 1024*4
constexpr size_t OFF_SGIDX   = OFF_SSCORE + 4096;          // 1024*4
constexpr size_t OFF_SLABEL  = OFF_SGIDX + 4096;           // 1024*4
constexpr size_t OFF_BRAW    = OFF_SLABEL + 4096;          // 16384
constexpr size_t OFF_BNMS    = OFF_BRAW + 16384;           // 16384
constexpr size_t OFF_MASK    = OFF_BNMS + 16384;           // 1000*16*8 = 128000

__device__ __forceinline__ bool decode_box(int row, int c,
    const float* __restrict__ regr, const float* __restrict__ props,
    float W, float H, float4& b) {
  const float4 rr = *reinterpret_cast<const float4*>(regr + (size_t)row * (NCLS * 4) + c * 4);
  const float4 pp = *reinterpret_cast<const float4*>(props + (size_t)row * 4);
  float pw = pp.z - pp.x, ph = pp.w - pp.y;
  float cx = pp.x + 0.5f * pw, cy = pp.y + 0.5f * ph;
  float dx = rr.x / 10.0f, dy = rr.y / 10.0f;
  float dw = fminf(rr.z / 5.0f, LOGCLAMP);
  float dh = fminf(rr.w / 5.0f, LOGCLAMP);
  float pcx = dx * pw + cx, pcy = dy * ph + cy;
  float ppw = expf(dw) * pw, pph = expf(dh) * ph;
  float x1 = fminf(fmaxf(pcx - 0.5f * ppw, 0.f), W);
  float y1 = fminf(fmaxf(pcy - 0.5f * pph, 0.f), H);
  float x2 = fminf(fmaxf(pcx + 0.5f * ppw, 0.f), W);
  float y2 = fminf(fmaxf(pcy + 0.5f * pph, 0.f), H);
  b = make_float4(x1, y1, x2, y2);
  return (x2 - x1 >= 0.01f) && (y2 - y1 >= 0.01f);
}

// Pass 1: 16 threads/row, 6 classes/thread, no LDS, no block sync.
// 800K threads -> ~12 waves/SIMD; short chains; coalesced 64B/group loads.
__global__ __launch_bounds__(256)
void pass1_kernel(const float* __restrict__ logits,
                  const float* __restrict__ regr,
                  const float* __restrict__ props,
                  const int* __restrict__ p_imh,
                  const int* __restrict__ p_imw,
                  uint32_t* __restrict__ hist,
                  uint16_t* __restrict__ rowmax) {
  const int gt  = blockIdx.x * 256 + threadIdx.x;   // 3125*256 = 50000*16 exactly
  const int row = gt >> 4;
  const int sub = gt & 15;
  const float* lr = logits + (size_t)row * NCLS;

  float x[6];
  #pragma unroll
  for (int j = 0; j < 6; ++j) {
    int c = sub + 16 * j;
    x[j] = (c < NCLS) ? lr[c] : -INFINITY;
  }
  float m = x[0];
  #pragma unroll
  for (int j = 1; j < 6; ++j) m = fmaxf(m, x[j]);
  m = fmaxf(m, __shfl_xor(m, 1));
  m = fmaxf(m, __shfl_xor(m, 2));
  m = fmaxf(m, __shfl_xor(m, 4));
  m = fmaxf(m, __shfl_xor(m, 8));
  float e[6]; float s = 0.f;
  #pragma unroll
  for (int j = 0; j < 6; ++j) {
    e[j] = (sub + 16 * j < NCLS) ? expf(x[j] - m) : 0.f;
    s += e[j];
  }
  s += __shfl_xor(s, 1);
  s += __shfl_xor(s, 2);
  s += __shfl_xor(s, 4);
  s += __shfl_xor(s, 8);

  const float W = (float)(*p_imw), H = (float)(*p_imh);
  int maxbin = 0;
  #pragma unroll
  for (int j = 0; j < 6; ++j) {
    int c = sub + 16 * j;
    if (c >= 1 && c < NCLS) {
      float score = e[j] / s;
      if (score > 0.05f) {
        float4 b;
        if (decode_box(row, c, regr, props, W, H, b)) {
          uint32_t bin = (__float_as_uint(score) >> 14) - BIN_BASE;
          atomicAdd(&hist[bin], 1u);
          if ((int)bin > maxbin) maxbin = (int)bin;
        }
      }
    }
  }
  maxbin = max(maxbin, __shfl_xor(maxbin, 1));
  maxbin = max(maxbin, __shfl_xor(maxbin, 2));
  maxbin = max(maxbin, __shfl_xor(maxbin, 4));
  maxbin = max(maxbin, __shfl_xor(maxbin, 8));
  if (sub == 0) rowmax[row] = (uint16_t)maxbin;
}

__global__ __launch_bounds__(256)
void cutoff_kernel(const uint32_t* __restrict__ hist, uint32_t* __restrict__ cnt) {
  __shared__ uint32_t sh[256];
  const int t = threadIdx.x;
  uint32_t s = 0;
  for (int i = 0; i < 16; ++i) s += hist[t * 16 + i];
  sh[t] = s;
  __syncthreads();
  uint32_t v = s;
  for (int offn = 1; offn < 256; offn <<= 1) {
    uint32_t add = (t + offn < 256) ? sh[t + offn] : 0;
    __syncthreads();
    v += add;
    sh[t] = v;
    __syncthreads();
  }
  const uint32_t total = sh[0];
  if (total == 0) { if (t == 0) cnt[0] = 0xFFFFFFFFu; return; }
  const uint32_t target = total < (uint32_t)KPRE ? total : (uint32_t)KPRE;
  const uint32_t rs_t = sh[t];
  const uint32_t rs_n = (t < 255) ? sh[t + 1] : 0;
  if (rs_t >= target && rs_n < target) {
    uint32_t acc = rs_n;
    for (int b = 15; b >= 0; --b) {
      acc += hist[t * 16 + b];
      if (acc >= target) { cnt[0] = (uint32_t)(t * 16 + b); break; }
    }
  }
}

// Refine: rows with rowmax >= cutoff; 4 rows per wave via 16-lane groups.
// Arithmetic replicates pass1 op-for-op (serial-6 + shfl 1,2,4,8).
__global__ __launch_bounds__(256)
void refine_kernel(const float* __restrict__ logits,
                   const float* __restrict__ regr,
                   const float* __restrict__ props,
                   const int* __restrict__ p_imh,
                   const int* __restrict__ p_imw,
                   const uint16_t* __restrict__ rowmax,
                   uint32_t* __restrict__ cnt,
                   unsigned long long* __restrict__ compact) {
  const int t = threadIdx.x;
  const int lane = t & 63;
  const int g = lane >> 4;
  const int sub = lane & 15;
  const uint32_t cut = cnt[0];
  const int myrow0 = blockIdx.x * 256 + t;
  bool qual = (myrow0 < NROWS) && ((uint32_t)rowmax[myrow0] >= cut);
  unsigned long long bm = __ballot(qual);
  if (!bm) return;
  const int waveBase = blockIdx.x * 256 + (t & ~63);
  const float W = (float)(*p_imw), H = (float)(*p_imh);

  while (bm) {
    int bsel[4];
    #pragma unroll
    for (int k = 0; k < 4; ++k) {
      bsel[k] = bm ? (__ffsll((unsigned long long)bm) - 1) : -1;
      if (bm) bm &= bm - 1;
    }
    const int myb = bsel[g];
    const int row = waveBase + (myb >= 0 ? myb : 0);
    const float* lr = logits + (size_t)row * NCLS;

    float x[6];
    #pragma unroll
    for (int j = 0; j < 6; ++j) {
      int c = sub + 16 * j;
      x[j] = (c < NCLS) ? lr[c] : -INFINITY;
    }
    float m = x[0];
    #pragma unroll
    for (int j = 1; j < 6; ++j) m = fmaxf(m, x[j]);
    m = fmaxf(m, __shfl_xor(m, 1));
    m = fmaxf(m, __shfl_xor(m, 2));
    m = fmaxf(m, __shfl_xor(m, 4));
    m = fmaxf(m, __shfl_xor(m, 8));
    float e[6]; float s = 0.f;
    #pragma unroll
    for (int j = 0; j < 6; ++j) {
      e[j] = (sub + 16 * j < NCLS) ? expf(x[j] - m) : 0.f;
      s += e[j];
    }
    s += __shfl_xor(s, 1);
    s += __shfl_xor(s, 2);
    s += __shfl_xor(s, 4);
    s += __shfl_xor(s, 8);

    if (myb >= 0) {
      #pragma unroll
      for (int j = 0; j < 6; ++j) {
        int c = sub + 16 * j;
        if (c >= 1 && c < NCLS) {
          float score = e[j] / s;
          if (score > 0.05f) {
            float4 bb;
            if (decode_box(row, c, regr, props, W, H, bb)) {
              uint32_t bits = __float_as_uint(score);
              uint32_t bin = (bits >> 14) - BIN_BASE;
              if (bin >= cut) {
                uint32_t pos = atomicAdd(&cnt[1], 1u);
                if (pos < CAP) {
                  uint32_t gidx = (uint32_t)row * 90u + (uint32_t)(c - 1);
                  compact[pos] = ((unsigned long long)bits << 32) |
                                 (unsigned long long)(0xFFFFFFFFu - gidx);
                }
              }
            }
          }
        }
      }
    }
  }
}

// Bitonic sort (width = next pow2 >= count, >=1024) + prep (decode selected).
__global__ __launch_bounds__(1024)
void sort_prep_kernel(const unsigned long long* __restrict__ compact,
                      const uint32_t* __restrict__ cnt,
                      const float* __restrict__ regr, const float* __restrict__ props,
                      const int* __restrict__ p_imh, const int* __restrict__ p_imw,
                      float* __restrict__ sel_score, uint32_t* __restrict__ sel_gidx,
                      int* __restrict__ slabel, float4* __restrict__ braw,
                      float4* __restrict__ bnms) {
  __shared__ unsigned long long arr[CAP];
  const int t = threadIdx.x;
  const uint32_t M = cnt[1] < (uint32_t)CAP ? cnt[1] : (uint32_t)CAP;
  int P = 1024;
  while (P < (int)M) P <<= 1;
  for (int i = t; i < P; i += 1024) arr[i] = (i < (int)M) ? compact[i] : 0ull;
  __syncthreads();
  for (int k = 2; k <= P; k <<= 1) {
    for (int j = k >> 1; j > 0; j >>= 1) {
      for (int i = t; i < P; i += 1024) {
        int l = i ^ j;
        if (l > i) {
          unsigned long long A = arr[i], B = arr[l];
          bool up = ((i & k) == 0);
          if (up ? (A > B) : (A < B)) { arr[i] = B; arr[l] = A; }
        }
      }
      __syncthreads();
    }
  }
  if (t < KPRE) {
    unsigned long long en = arr[P - 1 - t];   // descending
    float sc; uint32_t g;
    if (en) { sc = __uint_as_float((uint32_t)(en >> 32)); g = 0xFFFFFFFFu - (uint32_t)en; }
    else    { sc = -1.f; g = 0xFFFFFFFFu; }
    sel_score[t] = sc;
    sel_gidx[t] = g;
    if (sc > 0.f) {
      int row = (int)(g / 90u);
      int c   = (int)(g % 90u) + 1;
      float W = (float)(*p_imw), H = (float)(*p_imh);
      float4 b;
      decode_box(row, c, regr, props, W, H, b);
      braw[t] = b;
      float offv = (float)c * (float)(*p_imw + *p_imh + 2);
      bnms[t] = make_float4(b.x + offv, b.y + offv, b.z + offv, b.w + offv);
      slabel[t] = c;
    } else {
      braw[t] = make_float4(0, 0, 0, 0);
      bnms[t] = make_float4(0, 0, 0, 0);
      slabel[t] = 0;
    }
  }
}

// 256 threads/block: 4 waves x 4 mask-words each -> short serial chain.
__global__ __launch_bounds__(256)
void iou_kernel(const float4* __restrict__ bnms, unsigned long long* __restrict__ mask) {
  const int i = blockIdx.x;
  const int lane = threadIdx.x & 63;
  const int wv = threadIdx.x >> 6;
  const float4 bi = bnms[i];
  const float areai = fmaxf(bi.z - bi.x, 0.f) * fmaxf(bi.w - bi.y, 0.f);
  #pragma unroll
  for (int ww = 0; ww < 4; ++ww) {
    int wd = wv * 4 + ww;
    int j = wd * 64 + lane;
    bool bit = false;
    if (j < KPRE && j > i) {
      float4 bj = bnms[j];
      float areaj = fmaxf(bj.z - bj.x, 0.f) * fmaxf(bj.w - bj.y, 0.f);
      float ltx = fmaxf(bi.x, bj.x), lty = fmaxf(bi.y, bj.y);
      float rbx = fminf(bi.z, bj.z), rby = fminf(bi.w, bj.w);
      float iw = fmaxf(rbx - ltx, 0.f), ih = fmaxf(rby - lty, 0.f);
      float inter = iw * ih;
      float iou = inter / (areai + areaj - inter + 1e-7f);
      bit = iou > 0.5f;
    }
    unsigned long long mword = __ballot(bit);
    if (lane == 0) mask[(size_t)i * 16 + wd] = mword;
  }
}

__global__ __launch_bounds__(64)
void greedy_kernel(const unsigned long long* __restrict__ mask,
                   const float* __restrict__ sel_score,
                   const int* __restrict__ slabel,
                   const float4* __restrict__ braw,
                   float* __restrict__ out) {
  const int lane = threadIdx.x;
  unsigned long long kw = 0ull;
  #pragma unroll
  for (int w = 0; w < 16; ++w) {
    int j = w * 64 + lane;
    bool b = (j < KPRE) && (sel_score[j] > 0.f);
    unsigned long long mword = __ballot(b);
    if (lane == w) kw = mword;
  }
  __shared__ int kept[NDET];
  int kc = 0;
  for (int base = 0; base < KPRE && kc < NDET; base += 8) {
    unsigned long long r0, r1, r2, r3, r4, r5, r6, r7;
    r0 = (lane < 16) ? mask[(size_t)(base + 0) * 16 + lane] : 0ull;
    r1 = (lane < 16) ? mask[(size_t)(base + 1) * 16 + lane] : 0ull;
    r2 = (lane < 16) ? mask[(size_t)(base + 2) * 16 + lane] : 0ull;
    r3 = (lane < 16) ? mask[(size_t)(base + 3) * 16 + lane] : 0ull;
    r4 = (lane < 16) ? mask[(size_t)(base + 4) * 16 + lane] : 0ull;
    r5 = (lane < 16) ? mask[(size_t)(base + 5) * 16 + lane] : 0ull;
    r6 = (lane < 16) ? mask[(size_t)(base + 6) * 16 + lane] : 0ull;
    r7 = (lane < 16) ? mask[(size_t)(base + 7) * 16 + lane] : 0ull;
    #pragma unroll
    for (int u = 0; u < 8; ++u) {
      unsigned long long ru = (u == 0) ? r0 : (u == 1) ? r1 : (u == 2) ? r2 :
                              (u == 3) ? r3 : (u == 4) ? r4 : (u == 5) ? r5 :
                              (u == 6) ? r6 : r7;
      int i = base + u;
      if (kc < NDET) {
        unsigned long long kwv = __shfl(kw, i >> 6);
        if ((kwv >> (i & 63)) & 1ull) {
          kw &= ~ru;
          if (lane == 0) kept[kc] = i;
          ++kc;
        }
      }
    }
  }
  __syncthreads();
  for (int t = lane; t < NDET; t += 64) {
    if (t < kc) {
      int i = kept[t];
      float4 b = braw[i];
      out[t * 4 + 0] = b.x; out[t * 4 + 1] = b.y;
      out[t * 4 + 2] = b.z; out[t * 4 + 3] = b.w;
      out[4 * NDET + t] = sel_score[i];
      out[5 * NDET + t] = (float)slabel[i];
    } else {
      out[t * 4 + 0] = 0.f; out[t * 4 + 1] = 0.f;
      out[t * 4 + 2] = 0.f; out[t * 4 + 3] = 0.f;
      out[4 * NDET + t] = 0.f;
      out[5 * NDET + t] = 0.f;
    }
  }
}

extern "C" void kernel_launch(void* const* d_in, const int* in_sizes, int n_in,
                              void* d_out, int out_size, void* d_ws, size_t ws_size,
                              hipStream_t stream) {
  const float* logits = (const float*)d_in[0];
  const float* regr   = (const float*)d_in[1];
  const float* props  = (const float*)d_in[2];
  const int*   p_imh  = (const int*)d_in[3];
  const int*   p_imw  = (const int*)d_in[4];
  float* out = (float*)d_out;

  uint8_t* ws = (uint8_t*)d_ws;
  uint32_t* hist = (uint32_t*)(ws + OFF_HIST);
  uint32_t* cnt  = (uint32_t*)(ws + OFF_CNT);
  uint16_t* rowmax = (uint16_t*)(ws + OFF_ROWMAX);
  unsigned long long* compact = (unsigned long long*)(ws + OFF_COMPACT);
  float*    sel_score = (float*)(ws + OFF_SSCORE);
  uint32_t* sel_gidx  = (uint32_t*)(ws + OFF_SGIDX);
  int*      slabel    = (int*)(ws + OFF_SLABEL);
  float4*   braw      = (float4*)(ws + OFF_BRAW);
  float4*   bnms      = (float4*)(ws + OFF_BNMS);
  unsigned long long* mask = (unsigned long long*)(ws + OFF_MASK);

  // zero histogram + counters every call (graph replays don't re-poison)
  hipMemsetAsync(ws, 0, OFF_CNT + 64, stream);

  pass1_kernel<<<(NROWS * 16) / 256, 256, 0, stream>>>(
      logits, regr, props, p_imh, p_imw, hist, rowmax);
  cutoff_kernel<<<1, 256, 0, stream>>>(hist, cnt);
  refine_kernel<<<(NROWS + 255) / 256, 256, 0, stream>>>(
      logits, regr, props, p_imh, p_imw, rowmax, cnt, compact);
  sort_prep_kernel<<<1, 1024, 0, stream>>>(compact, cnt, regr, props, p_imh, p_imw,
                                           sel_score, sel_gidx, slabel, braw, bnms);
  iou_kernel<<<KPRE, 256, 0, stream>>>(bnms, mask);
  greedy_kernel<<<1, 64, 0, stream>>>(mask, sel_score, slabel, braw, out);
}

// Round 4
// 163.719 us; speedup vs baseline: 1.5514x; 1.1608x over previous
//
#include <hip/hip_runtime.h>
#include <cstdint>

#define NROWS 50000
#define NCLS  91
#define KPRE  1000
#define NDET  100
#define CAP   4096
#define NBINS 512
#define BIN_OFF 7680u       // bin = (bits>>17) - 7680; scores (0.05,1] -> bins [166,448]
#define LOGCLAMP 4.135166556742356f
#define ITERS 4
#define ROWS_PER_BLOCK 64   // 16 rows per iter * 4 iters
#define NBLK 782            // ceil(50000/64)
#define PB 800              // padded stride (u16 elems) per bin row in partial hist

// ---- workspace layout (bytes) ----
constexpr size_t OFF_CNT     = 0;                      // 64 B: [0]=cutoff bin, [1]=compact count
constexpr size_t OFF_ROWMAX  = 64;                     // 50000*2 -> pad to 100096
constexpr size_t OFF_COMPACT = 100096;                 // CAP*8 = 32768
constexpr size_t OFF_SSCORE  = 132864;                 // 1024*4
constexpr size_t OFF_SGIDX   = 136960;                 // 1024*4
constexpr size_t OFF_SLABEL  = 141056;                 // 1024*4
constexpr size_t OFF_BRAW    = 145152;                 // 16384
constexpr size_t OFF_BNMS    = 161536;                 // 16384
constexpr size_t OFF_MASK    = 177920;                 // 1000*16*8 = 128000
constexpr size_t OFF_PARTIAL = 305920;                 // 512*800*2 = 819200 -> end ~1.07 MB

__device__ __forceinline__ bool decode_box(int row, int c,
    const float* __restrict__ regr, const float* __restrict__ props,
    float W, float H, float4& b) {
  const float4 rr = *reinterpret_cast<const float4*>(regr + (size_t)row * (NCLS * 4) + c * 4);
  const float4 pp = *reinterpret_cast<const float4*>(props + (size_t)row * 4);
  float pw = pp.z - pp.x, ph = pp.w - pp.y;
  float cx = pp.x + 0.5f * pw, cy = pp.y + 0.5f * ph;
  float dx = rr.x / 10.0f, dy = rr.y / 10.0f;
  float dw = fminf(rr.z / 5.0f, LOGCLAMP);
  float dh = fminf(rr.w / 5.0f, LOGCLAMP);
  float pcx = dx * pw + cx, pcy = dy * ph + cy;
  float ppw = expf(dw) * pw, pph = expf(dh) * ph;
  float x1 = fminf(fmaxf(pcx - 0.5f * ppw, 0.f), W);
  float y1 = fminf(fmaxf(pcy - 0.5f * pph, 0.f), H);
  float x2 = fminf(fmaxf(pcx + 0.5f * ppw, 0.f), W);
  float y2 = fminf(fmaxf(pcy + 0.5f * pph, 0.f), H);
  b = make_float4(x1, y1, x2, y2);
  return (x2 - x1 >= 0.01f) && (y2 - y1 >= 0.01f);
}

// Pass 1: 16 threads/row, 6 classes/thread, 64 rows/block over 4 prefetched iters.
// LDS histogram per block; u16 partial store; NO global atomics.
__global__ __launch_bounds__(256)
void pass1_kernel(const float* __restrict__ logits,
                  const float* __restrict__ regr,
                  const float* __restrict__ props,
                  const int* __restrict__ p_imh,
                  const int* __restrict__ p_imw,
                  uint16_t* __restrict__ partial,
                  uint16_t* __restrict__ rowmax) {
  __shared__ uint32_t hist[NBINS];
  const int t = threadIdx.x;
  hist[t] = 0;
  hist[t + 256] = 0;
  __syncthreads();

  const int sub  = t & 15;
  const int grp  = t >> 4;                       // 0..15
  const int row0 = blockIdx.x * ROWS_PER_BLOCK + grp;
  const float W = (float)(*p_imw), H = (float)(*p_imh);

  // prefetch iter 0
  float xn[6];
  {
    const int row = row0;
    const bool ok = row < NROWS;
    const float* lr = logits + (size_t)row * NCLS;
    #pragma unroll
    for (int j = 0; j < 6; ++j) {
      int c = sub + 16 * j;
      xn[j] = (ok && c < NCLS) ? lr[c] : -INFINITY;
    }
  }

  for (int it = 0; it < ITERS; ++it) {
    const int row = row0 + it * 16;
    float x[6];
    #pragma unroll
    for (int j = 0; j < 6; ++j) x[j] = xn[j];
    if (it + 1 < ITERS) {                        // prefetch next row's logits
      const int nrow = row0 + (it + 1) * 16;
      const bool ok = nrow < NROWS;
      const float* lr = logits + (size_t)nrow * NCLS;
      #pragma unroll
      for (int j = 0; j < 6; ++j) {
        int c = sub + 16 * j;
        xn[j] = (ok && c < NCLS) ? lr[c] : -INFINITY;
      }
    }
    if (row < NROWS) {
      float m = x[0];
      #pragma unroll
      for (int j = 1; j < 6; ++j) m = fmaxf(m, x[j]);
      m = fmaxf(m, __shfl_xor(m, 1));
      m = fmaxf(m, __shfl_xor(m, 2));
      m = fmaxf(m, __shfl_xor(m, 4));
      m = fmaxf(m, __shfl_xor(m, 8));
      float e[6]; float s = 0.f;
      #pragma unroll
      for (int j = 0; j < 6; ++j) {
        e[j] = (sub + 16 * j < NCLS) ? expf(x[j] - m) : 0.f;
        s += e[j];
      }
      s += __shfl_xor(s, 1);
      s += __shfl_xor(s, 2);
      s += __shfl_xor(s, 4);
      s += __shfl_xor(s, 8);

      int maxbin = 0;
      #pragma unroll
      for (int j = 0; j < 6; ++j) {
        int c = sub + 16 * j;
        if (c >= 1 && c < NCLS) {
          float score = e[j] / s;
          if (score > 0.05f) {
            float4 b;
            if (decode_box(row, c, regr, props, W, H, b)) {
              uint32_t bin = (__float_as_uint(score) >> 17) - BIN_OFF;
              atomicAdd(&hist[bin], 1u);         // LDS atomic, on-CU
              if ((int)bin > maxbin) maxbin = (int)bin;
            }
          }
        }
      }
      maxbin = max(maxbin, __shfl_xor(maxbin, 1));
      maxbin = max(maxbin, __shfl_xor(maxbin, 2));
      maxbin = max(maxbin, __shfl_xor(maxbin, 4));
      maxbin = max(maxbin, __shfl_xor(maxbin, 8));
      if (sub == 0) rowmax[row] = (uint16_t)maxbin;
    }
  }
  __syncthreads();
  // flush partial histogram: [bin][block] layout, u16
  const int blk = blockIdx.x;
  uint32_t v0 = hist[t], v1 = hist[t + 256];
  partial[(size_t)t * PB + blk]         = (uint16_t)(v0 > 65535u ? 65535u : v0);
  partial[(size_t)(t + 256) * PB + blk] = (uint16_t)(v1 > 65535u ? 65535u : v1);
}

// Reduce 782 partials per bin + suffix scan -> exact cutoff bin. No atomics.
__global__ __launch_bounds__(512)
void cutoff_kernel(const uint16_t* __restrict__ partial, uint32_t* __restrict__ cnt) {
  __shared__ uint32_t sh[NBINS];
  const int t = threadIdx.x;                     // t == bin
  const uint32_t* r32 = reinterpret_cast<const uint32_t*>(partial + (size_t)t * PB);
  uint32_t s = 0;
  #pragma unroll 4
  for (int k = 0; k < NBLK / 2; ++k) {           // 391 u32 = 782 u16
    uint32_t v = r32[k];
    s += (v & 0xffffu) + (v >> 16);
  }
  sh[t] = s;
  __syncthreads();
  uint32_t v = s;
  for (int off = 1; off < NBINS; off <<= 1) {
    uint32_t add = (t + off < NBINS) ? sh[t + off] : 0;
    __syncthreads();
    v += add;
    sh[t] = v;
    __syncthreads();
  }
  const uint32_t total = sh[0];
  if (total == 0) { if (t == 0) cnt[0] = 0xFFFFFFFFu; return; }
  const uint32_t target = total < (uint32_t)KPRE ? total : (uint32_t)KPRE;
  const uint32_t rs_t = sh[t];
  const uint32_t rs_n = (t < NBINS - 1) ? sh[t + 1] : 0;
  if (rs_t >= target && rs_n < target) cnt[0] = (uint32_t)t;
}

// Refine: rows with rowmax >= cutoff; 4 rows per wave via 16-lane groups.
// Arithmetic replicates pass1 op-for-op (serial-6 + shfl 1,2,4,8).
__global__ __launch_bounds__(256)
void refine_kernel(const float* __restrict__ logits,
                   const float* __restrict__ regr,
                   const float* __restrict__ props,
                   const int* __restrict__ p_imh,
                   const int* __restrict__ p_imw,
                   const uint16_t* __restrict__ rowmax,
                   uint32_t* __restrict__ cnt,
                   unsigned long long* __restrict__ compact) {
  const int t = threadIdx.x;
  const int lane = t & 63;
  const int g = lane >> 4;
  const int sub = lane & 15;
  const uint32_t cut = cnt[0];
  const int myrow0 = blockIdx.x * 256 + t;
  bool qual = (myrow0 < NROWS) && ((uint32_t)rowmax[myrow0] >= cut);
  unsigned long long bm = __ballot(qual);
  if (!bm) return;
  const int waveBase = blockIdx.x * 256 + (t & ~63);
  const float W = (float)(*p_imw), H = (float)(*p_imh);

  while (bm) {
    int bsel[4];
    #pragma unroll
    for (int k = 0; k < 4; ++k) {
      bsel[k] = bm ? (__ffsll((unsigned long long)bm) - 1) : -1;
      if (bm) bm &= bm - 1;
    }
    const int myb = bsel[g];
    const int row = waveBase + (myb >= 0 ? myb : 0);
    const float* lr = logits + (size_t)row * NCLS;

    float x[6];
    #pragma unroll
    for (int j = 0; j < 6; ++j) {
      int c = sub + 16 * j;
      x[j] = (c < NCLS) ? lr[c] : -INFINITY;
    }
    float m = x[0];
    #pragma unroll
    for (int j = 1; j < 6; ++j) m = fmaxf(m, x[j]);
    m = fmaxf(m, __shfl_xor(m, 1));
    m = fmaxf(m, __shfl_xor(m, 2));
    m = fmaxf(m, __shfl_xor(m, 4));
    m = fmaxf(m, __shfl_xor(m, 8));
    float e[6]; float s = 0.f;
    #pragma unroll
    for (int j = 0; j < 6; ++j) {
      e[j] = (sub + 16 * j < NCLS) ? expf(x[j] - m) : 0.f;
      s += e[j];
    }
    s += __shfl_xor(s, 1);
    s += __shfl_xor(s, 2);
    s += __shfl_xor(s, 4);
    s += __shfl_xor(s, 8);

    if (myb >= 0) {
      #pragma unroll
      for (int j = 0; j < 6; ++j) {
        int c = sub + 16 * j;
        if (c >= 1 && c < NCLS) {
          float score = e[j] / s;
          if (score > 0.05f) {
            float4 bb;
            if (decode_box(row, c, regr, props, W, H, bb)) {
              uint32_t bits = __float_as_uint(score);
              uint32_t bin = (bits >> 17) - BIN_OFF;
              if (bin >= cut) {
                uint32_t pos = atomicAdd(&cnt[1], 1u);
                if (pos < CAP) {
                  uint32_t gidx = (uint32_t)row * 90u + (uint32_t)(c - 1);
                  compact[pos] = ((unsigned long long)bits << 32) |
                                 (unsigned long long)(0xFFFFFFFFu - gidx);
                }
              }
            }
          }
        }
      }
    }
  }
}

// Bitonic sort (width = next pow2 >= count, >=1024) + prep (decode selected).
__global__ __launch_bounds__(1024)
void sort_prep_kernel(const unsigned long long* __restrict__ compact,
                      const uint32_t* __restrict__ cnt,
                      const float* __restrict__ regr, const float* __restrict__ props,
                      const int* __restrict__ p_imh, const int* __restrict__ p_imw,
                      float* __restrict__ sel_score, uint32_t* __restrict__ sel_gidx,
                      int* __restrict__ slabel, float4* __restrict__ braw,
                      float4* __restrict__ bnms) {
  __shared__ unsigned long long arr[CAP];
  const int t = threadIdx.x;
  const uint32_t M = cnt[1] < (uint32_t)CAP ? cnt[1] : (uint32_t)CAP;
  int P = 1024;
  while (P < (int)M) P <<= 1;
  for (int i = t; i < P; i += 1024) arr[i] = (i < (int)M) ? compact[i] : 0ull;
  __syncthreads();
  for (int k = 2; k <= P; k <<= 1) {
    for (int j = k >> 1; j > 0; j >>= 1) {
      for (int i = t; i < P; i += 1024) {
        int l = i ^ j;
        if (l > i) {
          unsigned long long A = arr[i], B = arr[l];
          bool up = ((i & k) == 0);
          if (up ? (A > B) : (A < B)) { arr[i] = B; arr[l] = A; }
        }
      }
      __syncthreads();
    }
  }
  if (t < KPRE) {
    unsigned long long en = arr[P - 1 - t];   // descending
    float sc; uint32_t g;
    if (en) { sc = __uint_as_float((uint32_t)(en >> 32)); g = 0xFFFFFFFFu - (uint32_t)en; }
    else    { sc = -1.f; g = 0xFFFFFFFFu; }
    sel_score[t] = sc;
    sel_gidx[t] = g;
    if (sc > 0.f) {
      int row = (int)(g / 90u);
      int c   = (int)(g % 90u) + 1;
      float W = (float)(*p_imw), H = (float)(*p_imh);
      float4 b;
      decode_box(row, c, regr, props, W, H, b);
      braw[t] = b;
      float offv = (float)c * (float)(*p_imw + *p_imh + 2);
      bnms[t] = make_float4(b.x + offv, b.y + offv, b.z + offv, b.w + offv);
      slabel[t] = c;
    } else {
      braw[t] = make_float4(0, 0, 0, 0);
      bnms[t] = make_float4(0, 0, 0, 0);
      slabel[t] = 0;
    }
  }
}

// 256 threads/block: 4 waves x 4 mask-words each.
__global__ __launch_bounds__(256)
void iou_kernel(const float4* __restrict__ bnms, unsigned long long* __restrict__ mask) {
  const int i = blockIdx.x;
  const int lane = threadIdx.x & 63;
  const int wv = threadIdx.x >> 6;
  const float4 bi = bnms[i];
  const float areai = fmaxf(bi.z - bi.x, 0.f) * fmaxf(bi.w - bi.y, 0.f);
  #pragma unroll
  for (int ww = 0; ww < 4; ++ww) {
    int wd = wv * 4 + ww;
    int j = wd * 64 + lane;
    bool bit = false;
    if (j < KPRE && j > i) {
      float4 bj = bnms[j];
      float areaj = fmaxf(bj.z - bj.x, 0.f) * fmaxf(bj.w - bj.y, 0.f);
      float ltx = fmaxf(bi.x, bj.x), lty = fmaxf(bi.y, bj.y);
      float rbx = fminf(bi.z, bj.z), rby = fminf(bi.w, bj.w);
      float iw = fmaxf(rbx - ltx, 0.f), ih = fmaxf(rby - lty, 0.f);
      float inter = iw * ih;
      float iou = inter / (areai + areaj - inter + 1e-7f);
      bit = iou > 0.5f;
    }
    unsigned long long mword = __ballot(bit);
    if (lane == 0) mask[(size_t)i * 16 + wd] = mword;
  }
}

__global__ __launch_bounds__(64)
void greedy_kernel(const unsigned long long* __restrict__ mask,
                   const float* __restrict__ sel_score,
                   const int* __restrict__ slabel,
                   const float4* __restrict__ braw,
                   float* __restrict__ out) {
  const int lane = threadIdx.x;
  unsigned long long kw = 0ull;
  #pragma unroll
  for (int w = 0; w < 16; ++w) {
    int j = w * 64 + lane;
    bool b = (j < KPRE) && (sel_score[j] > 0.f);
    unsigned long long mword = __ballot(b);
    if (lane == w) kw = mword;
  }
  __shared__ int kept[NDET];
  int kc = 0;
  for (int base = 0; base < KPRE && kc < NDET; base += 8) {
    unsigned long long r0, r1, r2, r3, r4, r5, r6, r7;
    r0 = (lane < 16) ? mask[(size_t)(base + 0) * 16 + lane] : 0ull;
    r1 = (lane < 16) ? mask[(size_t)(base + 1) * 16 + lane] : 0ull;
    r2 = (lane < 16) ? mask[(size_t)(base + 2) * 16 + lane] : 0ull;
    r3 = (lane < 16) ? mask[(size_t)(base + 3) * 16 + lane] : 0ull;
    r4 = (lane < 16) ? mask[(size_t)(base + 4) * 16 + lane] : 0ull;
    r5 = (lane < 16) ? mask[(size_t)(base + 5) * 16 + lane] : 0ull;
    r6 = (lane < 16) ? mask[(size_t)(base + 6) * 16 + lane] : 0ull;
    r7 = (lane < 16) ? mask[(size_t)(base + 7) * 16 + lane] : 0ull;
    #pragma unroll
    for (int u = 0; u < 8; ++u) {
      unsigned long long ru = (u == 0) ? r0 : (u == 1) ? r1 : (u == 2) ? r2 :
                              (u == 3) ? r3 : (u == 4) ? r4 : (u == 5) ? r5 :
                              (u == 6) ? r6 : r7;
      int i = base + u;
      if (kc < NDET) {
        unsigned long long kwv = __shfl(kw, i >> 6);
        if ((kwv >> (i & 63)) & 1ull) {
          kw &= ~ru;
          if (lane == 0) kept[kc] = i;
          ++kc;
        }
      }
    }
  }
  __syncthreads();
  for (int t = lane; t < NDET; t += 64) {
    if (t < kc) {
      int i = kept[t];
      float4 b = braw[i];
      out[t * 4 + 0] = b.x; out[t * 4 + 1] = b.y;
      out[t * 4 + 2] = b.z; out[t * 4 + 3] = b.w;
      out[4 * NDET + t] = sel_score[i];
      out[5 * NDET + t] = (float)slabel[i];
    } else {
      out[t * 4 + 0] = 0.f; out[t * 4 + 1] = 0.f;
      out[t * 4 + 2] = 0.f; out[t * 4 + 3] = 0.f;
      out[4 * NDET + t] = 0.f;
      out[5 * NDET + t] = 0.f;
    }
  }
}

extern "C" void kernel_launch(void* const* d_in, const int* in_sizes, int n_in,
                              void* d_out, int out_size, void* d_ws, size_t ws_size,
                              hipStream_t stream) {
  const float* logits = (const float*)d_in[0];
  const float* regr   = (const float*)d_in[1];
  const float* props  = (const float*)d_in[2];
  const int*   p_imh  = (const int*)d_in[3];
  const int*   p_imw  = (const int*)d_in[4];
  float* out = (float*)d_out;

  uint8_t* ws = (uint8_t*)d_ws;
  uint32_t* cnt  = (uint32_t*)(ws + OFF_CNT);
  uint16_t* rowmax = (uint16_t*)(ws + OFF_ROWMAX);
  unsigned long long* compact = (unsigned long long*)(ws + OFF_COMPACT);
  float*    sel_score = (float*)(ws + OFF_SSCORE);
  uint32_t* sel_gidx  = (uint32_t*)(ws + OFF_SGIDX);
  int*      slabel    = (int*)(ws + OFF_SLABEL);
  float4*   braw      = (float4*)(ws + OFF_BRAW);
  float4*   bnms      = (float4*)(ws + OFF_BNMS);
  unsigned long long* mask = (unsigned long long*)(ws + OFF_MASK);
  uint16_t* partial   = (uint16_t*)(ws + OFF_PARTIAL);

  // zero counters every call (graph replays don't re-poison)
  hipMemsetAsync(cnt, 0, 64, stream);

  pass1_kernel<<<NBLK, 256, 0, stream>>>(
      logits, regr, props, p_imh, p_imw, partial, rowmax);
  cutoff_kernel<<<1, 512, 0, stream>>>(partial, cnt);
  refine_kernel<<<(NROWS + 255) / 256, 256, 0, stream>>>(
      logits, regr, props, p_imh, p_imw, rowmax, cnt, compact);
  sort_prep_kernel<<<1, 1024, 0, stream>>>(compact, cnt, regr, props, p_imh, p_imw,
                                           sel_score, sel_gidx, slabel, braw, bnms);
  iou_kernel<<<KPRE, 256, 0, stream>>>(bnms, mask);
  greedy_kernel<<<1, 64, 0, stream>>>(mask, sel_score, slabel, braw, out);
}

// Round 5
// 105.972 us; speedup vs baseline: 2.3967x; 1.5449x over previous
//
#include <hip/hip_runtime.h>
#include <cstdint>

#define NROWS 50000
#define NCLS  91
#define KPRE  1000
#define NDET  100
#define CAP   4096
#define NBINS 512
#define BIN_OFF 7680u       // bin = (bits>>17) - 7680; scores (0.05,1] -> bins [166,448]
#define LOGCLAMP 4.135166556742356f
#define ITERS 4
#define ROWS_PER_BLOCK 64   // 16 rows per iter * 4 iters
#define NBLK 782            // ceil(50000/64)
#define PB 800              // padded stride (u16 elems) per bin row in partial hist
#define GCHUNK 128          // greedy: mask rows per LDS chunk

// ---- workspace layout (bytes) ----
constexpr size_t OFF_CNT     = 0;                      // 64 B: [0]=cutoff bin, [1]=compact count
constexpr size_t OFF_ROWMAX  = 64;                     // 50000*2 -> pad to 100096
constexpr size_t OFF_COMPACT = 100096;                 // CAP*8 = 32768
constexpr size_t OFF_SSCORE  = 132864;                 // 1024*4
constexpr size_t OFF_SGIDX   = 136960;                 // 1024*4
constexpr size_t OFF_SLABEL  = 141056;                 // 1024*4
constexpr size_t OFF_BRAW    = 145152;                 // 16384
constexpr size_t OFF_BNMS    = 161536;                 // 16384
constexpr size_t OFF_MASK    = 177920;                 // 1000*16*8 = 128000
constexpr size_t OFF_PARTIAL = 305920;                 // 512*800*2 = 819200
constexpr size_t OFF_HIST512 = 1125120;                // 512*4 = 2048 -> end ~1.13 MB

__device__ __forceinline__ bool decode_box(int row, int c,
    const float* __restrict__ regr, const float* __restrict__ props,
    float W, float H, float4& b) {
  const float4 rr = *reinterpret_cast<const float4*>(regr + (size_t)row * (NCLS * 4) + c * 4);
  const float4 pp = *reinterpret_cast<const float4*>(props + (size_t)row * 4);
  float pw = pp.z - pp.x, ph = pp.w - pp.y;
  float cx = pp.x + 0.5f * pw, cy = pp.y + 0.5f * ph;
  float dx = rr.x / 10.0f, dy = rr.y / 10.0f;
  float dw = fminf(rr.z / 5.0f, LOGCLAMP);
  float dh = fminf(rr.w / 5.0f, LOGCLAMP);
  float pcx = dx * pw + cx, pcy = dy * ph + cy;
  float ppw = expf(dw) * pw, pph = expf(dh) * ph;
  float x1 = fminf(fmaxf(pcx - 0.5f * ppw, 0.f), W);
  float y1 = fminf(fmaxf(pcy - 0.5f * pph, 0.f), H);
  float x2 = fminf(fmaxf(pcx + 0.5f * ppw, 0.f), W);
  float y2 = fminf(fmaxf(pcy + 0.5f * pph, 0.f), H);
  b = make_float4(x1, y1, x2, y2);
  return (x2 - x1 >= 0.01f) && (y2 - y1 >= 0.01f);
}

// Pass 1: 16 threads/row, 6 classes/thread, 64 rows/block over 4 prefetched iters.
// LDS histogram per block; u16 partial store; NO global atomics.
__global__ __launch_bounds__(256)
void pass1_kernel(const float* __restrict__ logits,
                  const float* __restrict__ regr,
                  const float* __restrict__ props,
                  const int* __restrict__ p_imh,
                  const int* __restrict__ p_imw,
                  uint16_t* __restrict__ partial,
                  uint16_t* __restrict__ rowmax) {
  __shared__ uint32_t hist[NBINS];
  const int t = threadIdx.x;
  hist[t] = 0;
  hist[t + 256] = 0;
  __syncthreads();

  const int sub  = t & 15;
  const int grp  = t >> 4;                       // 0..15
  const int row0 = blockIdx.x * ROWS_PER_BLOCK + grp;
  const float W = (float)(*p_imw), H = (float)(*p_imh);

  // prefetch iter 0
  float xn[6];
  {
    const int row = row0;
    const bool ok = row < NROWS;
    const float* lr = logits + (size_t)row * NCLS;
    #pragma unroll
    for (int j = 0; j < 6; ++j) {
      int c = sub + 16 * j;
      xn[j] = (ok && c < NCLS) ? lr[c] : -INFINITY;
    }
  }

  for (int it = 0; it < ITERS; ++it) {
    const int row = row0 + it * 16;
    float x[6];
    #pragma unroll
    for (int j = 0; j < 6; ++j) x[j] = xn[j];
    if (it + 1 < ITERS) {                        // prefetch next row's logits
      const int nrow = row0 + (it + 1) * 16;
      const bool ok = nrow < NROWS;
      const float* lr = logits + (size_t)nrow * NCLS;
      #pragma unroll
      for (int j = 0; j < 6; ++j) {
        int c = sub + 16 * j;
        xn[j] = (ok && c < NCLS) ? lr[c] : -INFINITY;
      }
    }
    if (row < NROWS) {
      float m = x[0];
      #pragma unroll
      for (int j = 1; j < 6; ++j) m = fmaxf(m, x[j]);
      m = fmaxf(m, __shfl_xor(m, 1));
      m = fmaxf(m, __shfl_xor(m, 2));
      m = fmaxf(m, __shfl_xor(m, 4));
      m = fmaxf(m, __shfl_xor(m, 8));
      float e[6]; float s = 0.f;
      #pragma unroll
      for (int j = 0; j < 6; ++j) {
        e[j] = (sub + 16 * j < NCLS) ? expf(x[j] - m) : 0.f;
        s += e[j];
      }
      s += __shfl_xor(s, 1);
      s += __shfl_xor(s, 2);
      s += __shfl_xor(s, 4);
      s += __shfl_xor(s, 8);

      int maxbin = 0;
      #pragma unroll
      for (int j = 0; j < 6; ++j) {
        int c = sub + 16 * j;
        if (c >= 1 && c < NCLS) {
          float score = e[j] / s;
          if (score > 0.05f) {
            float4 b;
            if (decode_box(row, c, regr, props, W, H, b)) {
              uint32_t bin = (__float_as_uint(score) >> 17) - BIN_OFF;
              atomicAdd(&hist[bin], 1u);         // LDS atomic, on-CU
              if ((int)bin > maxbin) maxbin = (int)bin;
            }
          }
        }
      }
      maxbin = max(maxbin, __shfl_xor(maxbin, 1));
      maxbin = max(maxbin, __shfl_xor(maxbin, 2));
      maxbin = max(maxbin, __shfl_xor(maxbin, 4));
      maxbin = max(maxbin, __shfl_xor(maxbin, 8));
      if (sub == 0) rowmax[row] = (uint16_t)maxbin;
    }
  }
  __syncthreads();
  // flush partial histogram: [bin][block] layout, u16
  const int blk = blockIdx.x;
  uint32_t v0 = hist[t], v1 = hist[t + 256];
  partial[(size_t)t * PB + blk]         = (uint16_t)(v0 > 65535u ? 65535u : v0);
  partial[(size_t)(t + 256) * PB + blk] = (uint16_t)(v1 > 65535u ? 65535u : v1);
}

// 512 blocks: block b sums bin b's 782 partials (coalesced u32 reads).
__global__ __launch_bounds__(64)
void binsum_kernel(const uint16_t* __restrict__ partial, uint32_t* __restrict__ hist512) {
  const int b = blockIdx.x;
  const uint32_t* r32 = reinterpret_cast<const uint32_t*>(partial + (size_t)b * PB);
  uint32_t s = 0;
  for (int k = threadIdx.x; k < NBLK / 2; k += 64) {   // 391 u32 = 782 u16
    uint32_t v = r32[k];
    s += (v & 0xffffu) + (v >> 16);
  }
  #pragma unroll
  for (int off = 32; off; off >>= 1) s += __shfl_xor(s, off);
  if (threadIdx.x == 0) hist512[b] = s;
}

// 1 block: suffix scan of 512-bin histogram -> exact cutoff bin.
__global__ __launch_bounds__(512)
void scan_kernel(const uint32_t* __restrict__ hist512, uint32_t* __restrict__ cnt) {
  __shared__ uint32_t sh[NBINS];
  const int t = threadIdx.x;
  uint32_t s = hist512[t];
  sh[t] = s;
  __syncthreads();
  uint32_t v = s;
  for (int off = 1; off < NBINS; off <<= 1) {
    uint32_t add = (t + off < NBINS) ? sh[t + off] : 0;
    __syncthreads();
    v += add;
    sh[t] = v;
    __syncthreads();
  }
  const uint32_t total = sh[0];
  if (total == 0) { if (t == 0) cnt[0] = 0xFFFFFFFFu; return; }
  const uint32_t target = total < (uint32_t)KPRE ? total : (uint32_t)KPRE;
  const uint32_t rs_t = sh[t];
  const uint32_t rs_n = (t < NBINS - 1) ? sh[t + 1] : 0;
  if (rs_t >= target && rs_n < target) cnt[0] = (uint32_t)t;
}

// Refine: rows with rowmax >= cutoff; 4 rows per wave via 16-lane groups.
// Arithmetic replicates pass1 op-for-op (serial-6 + shfl 1,2,4,8).
__global__ __launch_bounds__(256)
void refine_kernel(const float* __restrict__ logits,
                   const float* __restrict__ regr,
                   const float* __restrict__ props,
                   const int* __restrict__ p_imh,
                   const int* __restrict__ p_imw,
                   const uint16_t* __restrict__ rowmax,
                   uint32_t* __restrict__ cnt,
                   unsigned long long* __restrict__ compact) {
  const int t = threadIdx.x;
  const int lane = t & 63;
  const int g = lane >> 4;
  const int sub = lane & 15;
  const uint32_t cut = cnt[0];
  const int myrow0 = blockIdx.x * 256 + t;
  bool qual = (myrow0 < NROWS) && ((uint32_t)rowmax[myrow0] >= cut);
  unsigned long long bm = __ballot(qual);
  if (!bm) return;
  const int waveBase = blockIdx.x * 256 + (t & ~63);
  const float W = (float)(*p_imw), H = (float)(*p_imh);

  while (bm) {
    int bsel[4];
    #pragma unroll
    for (int k = 0; k < 4; ++k) {
      bsel[k] = bm ? (__ffsll((unsigned long long)bm) - 1) : -1;
      if (bm) bm &= bm - 1;
    }
    const int myb = bsel[g];
    const int row = waveBase + (myb >= 0 ? myb : 0);
    const float* lr = logits + (size_t)row * NCLS;

    float x[6];
    #pragma unroll
    for (int j = 0; j < 6; ++j) {
      int c = sub + 16 * j;
      x[j] = (c < NCLS) ? lr[c] : -INFINITY;
    }
    float m = x[0];
    #pragma unroll
    for (int j = 1; j < 6; ++j) m = fmaxf(m, x[j]);
    m = fmaxf(m, __shfl_xor(m, 1));
    m = fmaxf(m, __shfl_xor(m, 2));
    m = fmaxf(m, __shfl_xor(m, 4));
    m = fmaxf(m, __shfl_xor(m, 8));
    float e[6]; float s = 0.f;
    #pragma unroll
    for (int j = 0; j < 6; ++j) {
      e[j] = (sub + 16 * j < NCLS) ? expf(x[j] - m) : 0.f;
      s += e[j];
    }
    s += __shfl_xor(s, 1);
    s += __shfl_xor(s, 2);
    s += __shfl_xor(s, 4);
    s += __shfl_xor(s, 8);

    if (myb >= 0) {
      #pragma unroll
      for (int j = 0; j < 6; ++j) {
        int c = sub + 16 * j;
        if (c >= 1 && c < NCLS) {
          float score = e[j] / s;
          if (score > 0.05f) {
            float4 bb;
            if (decode_box(row, c, regr, props, W, H, bb)) {
              uint32_t bits = __float_as_uint(score);
              uint32_t bin = (bits >> 17) - BIN_OFF;
              if (bin >= cut) {
                uint32_t pos = atomicAdd(&cnt[1], 1u);
                if (pos < CAP) {
                  uint32_t gidx = (uint32_t)row * 90u + (uint32_t)(c - 1);
                  compact[pos] = ((unsigned long long)bits << 32) |
                                 (unsigned long long)(0xFFFFFFFFu - gidx);
                }
              }
            }
          }
        }
      }
    }
  }
}

// Bitonic sort (width = next pow2 >= count, >=1024) + prep (decode selected).
__global__ __launch_bounds__(1024)
void sort_prep_kernel(const unsigned long long* __restrict__ compact,
                      const uint32_t* __restrict__ cnt,
                      const float* __restrict__ regr, const float* __restrict__ props,
                      const int* __restrict__ p_imh, const int* __restrict__ p_imw,
                      float* __restrict__ sel_score, uint32_t* __restrict__ sel_gidx,
                      int* __restrict__ slabel, float4* __restrict__ braw,
                      float4* __restrict__ bnms) {
  __shared__ unsigned long long arr[CAP];
  const int t = threadIdx.x;
  const uint32_t M = cnt[1] < (uint32_t)CAP ? cnt[1] : (uint32_t)CAP;
  int P = 1024;
  while (P < (int)M) P <<= 1;
  for (int i = t; i < P; i += 1024) arr[i] = (i < (int)M) ? compact[i] : 0ull;
  __syncthreads();
  for (int k = 2; k <= P; k <<= 1) {
    for (int j = k >> 1; j > 0; j >>= 1) {
      for (int i = t; i < P; i += 1024) {
        int l = i ^ j;
        if (l > i) {
          unsigned long long A = arr[i], B = arr[l];
          bool up = ((i & k) == 0);
          if (up ? (A > B) : (A < B)) { arr[i] = B; arr[l] = A; }
        }
      }
      __syncthreads();
    }
  }
  if (t < KPRE) {
    unsigned long long en = arr[P - 1 - t];   // descending
    float sc; uint32_t g;
    if (en) { sc = __uint_as_float((uint32_t)(en >> 32)); g = 0xFFFFFFFFu - (uint32_t)en; }
    else    { sc = -1.f; g = 0xFFFFFFFFu; }
    sel_score[t] = sc;
    sel_gidx[t] = g;
    if (sc > 0.f) {
      int row = (int)(g / 90u);
      int c   = (int)(g % 90u) + 1;
      float W = (float)(*p_imw), H = (float)(*p_imh);
      float4 b;
      decode_box(row, c, regr, props, W, H, b);
      braw[t] = b;
      float offv = (float)c * (float)(*p_imw + *p_imh + 2);
      bnms[t] = make_float4(b.x + offv, b.y + offv, b.z + offv, b.w + offv);
      slabel[t] = c;
    } else {
      braw[t] = make_float4(0, 0, 0, 0);
      bnms[t] = make_float4(0, 0, 0, 0);
      slabel[t] = 0;
    }
  }
}

// 256 threads/block: 4 waves x 4 mask-words each.
__global__ __launch_bounds__(256)
void iou_kernel(const float4* __restrict__ bnms, unsigned long long* __restrict__ mask) {
  const int i = blockIdx.x;
  const int lane = threadIdx.x & 63;
  const int wv = threadIdx.x >> 6;
  const float4 bi = bnms[i];
  const float areai = fmaxf(bi.z - bi.x, 0.f) * fmaxf(bi.w - bi.y, 0.f);
  #pragma unroll
  for (int ww = 0; ww < 4; ++ww) {
    int wd = wv * 4 + ww;
    int j = wd * 64 + lane;
    bool bit = false;
    if (j < KPRE && j > i) {
      float4 bj = bnms[j];
      float areaj = fmaxf(bj.z - bj.x, 0.f) * fmaxf(bj.w - bj.y, 0.f);
      float ltx = fmaxf(bi.x, bj.x), lty = fmaxf(bi.y, bj.y);
      float rbx = fminf(bi.z, bj.z), rby = fminf(bi.w, bj.w);
      float iw = fmaxf(rbx - ltx, 0.f), ih = fmaxf(rby - lty, 0.f);
      float inter = iw * ih;
      float iou = inter / (areai + areaj - inter + 1e-7f);
      bit = iou > 0.5f;
    }
    unsigned long long mword = __ballot(bit);
    if (lane == 0) mask[(size_t)i * 16 + wd] = mword;
  }
}

// Greedy NMS: wave 0 scans from LDS; waves 1-3 prefetch next mask chunk.
__global__ __launch_bounds__(256)
void greedy_kernel(const unsigned long long* __restrict__ mask,
                   const float* __restrict__ sel_score,
                   const int* __restrict__ slabel,
                   const float4* __restrict__ braw,
                   float* __restrict__ out) {
  __shared__ ulonglong2 buf[2][GCHUNK * 8];       // 2 x 16 KB
  __shared__ int kept[NDET];
  __shared__ int s_done;
  const int t = threadIdx.x;
  const int lane = t & 63;
  const int wv = t >> 6;
  const ulonglong2* gm2 = reinterpret_cast<const ulonglong2*>(mask);
  constexpr int NCHUNK = (KPRE + GCHUNK - 1) / GCHUNK;   // 8

  // keep0 bitset: each wave builds its own copy; wave 0's is used
  unsigned long long kw = 0ull;
  #pragma unroll
  for (int w = 0; w < 16; ++w) {
    int j = w * 64 + lane;
    bool b = (j < KPRE) && (sel_score[j] > 0.f);
    unsigned long long mword = __ballot(b);
    if (lane == w) kw = mword;
  }
  if (t == 0) s_done = 0;

  // stage chunk 0 (all 256 threads; 1024 ull2 -> 4 each, independent loads)
  {
    int rows = (KPRE < GCHUNK) ? KPRE : GCHUNK;
    int n2 = rows * 8;
    for (int k = t; k < n2; k += 256) buf[0][k] = gm2[k];
  }
  __syncthreads();

  int kc = 0;
  for (int c = 0; c < NCHUNK; ++c) {
    // waves 1-3: prefetch chunk c+1 while wave 0 scans chunk c
    if (wv > 0 && c + 1 < NCHUNK) {
      int rows = KPRE - (c + 1) * GCHUNK;
      if (rows > GCHUNK) rows = GCHUNK;
      int n2 = rows * 8;
      size_t gbase = (size_t)(c + 1) * GCHUNK * 8;
      for (int k = t - 64; k < n2; k += 192) buf[(c + 1) & 1][k] = gm2[gbase + k];
    }
    if (wv == 0) {
      const unsigned long long* bb =
          reinterpret_cast<const unsigned long long*>(buf[c & 1]);
      int rows = KPRE - c * GCHUNK;
      if (rows > GCHUNK) rows = GCHUNK;
      unsigned long long curm = (lane < 16) ? bb[lane] : 0ull;   // row 0 of chunk
      for (int r = 0; r < rows; ++r) {
        unsigned long long nxt =
            (lane < 16 && r + 1 < rows) ? bb[(r + 1) * 16 + lane] : 0ull;
        int i = c * GCHUNK + r;
        unsigned long long kwv = __shfl(kw, i >> 6);
        if ((kwv >> (i & 63)) & 1ull) {
          if (lane == 0) kept[kc] = i;
          kw &= ~curm;
          ++kc;
          if (kc >= NDET) { if (lane == 0) s_done = 1; break; }
        }
        curm = nxt;
      }
    }
    __syncthreads();
    if (s_done) break;
  }

  if (wv == 0) {
    for (int q = lane; q < NDET; q += 64) {
      if (q < kc) {
        int i = kept[q];
        float4 b = braw[i];
        out[q * 4 + 0] = b.x; out[q * 4 + 1] = b.y;
        out[q * 4 + 2] = b.z; out[q * 4 + 3] = b.w;
        out[4 * NDET + q] = sel_score[i];
        out[5 * NDET + q] = (float)slabel[i];
      } else {
        out[q * 4 + 0] = 0.f; out[q * 4 + 1] = 0.f;
        out[q * 4 + 2] = 0.f; out[q * 4 + 3] = 0.f;
        out[4 * NDET + q] = 0.f;
        out[5 * NDET + q] = 0.f;
      }
    }
  }
}

extern "C" void kernel_launch(void* const* d_in, const int* in_sizes, int n_in,
                              void* d_out, int out_size, void* d_ws, size_t ws_size,
                              hipStream_t stream) {
  const float* logits = (const float*)d_in[0];
  const float* regr   = (const float*)d_in[1];
  const float* props  = (const float*)d_in[2];
  const int*   p_imh  = (const int*)d_in[3];
  const int*   p_imw  = (const int*)d_in[4];
  float* out = (float*)d_out;

  uint8_t* ws = (uint8_t*)d_ws;
  uint32_t* cnt  = (uint32_t*)(ws + OFF_CNT);
  uint16_t* rowmax = (uint16_t*)(ws + OFF_ROWMAX);
  unsigned long long* compact = (unsigned long long*)(ws + OFF_COMPACT);
  float*    sel_score = (float*)(ws + OFF_SSCORE);
  uint32_t* sel_gidx  = (uint32_t*)(ws + OFF_SGIDX);
  int*      slabel    = (int*)(ws + OFF_SLABEL);
  float4*   braw      = (float4*)(ws + OFF_BRAW);
  float4*   bnms      = (float4*)(ws + OFF_BNMS);
  unsigned long long* mask = (unsigned long long*)(ws + OFF_MASK);
  uint16_t* partial   = (uint16_t*)(ws + OFF_PARTIAL);
  uint32_t* hist512   = (uint32_t*)(ws + OFF_HIST512);

  // zero counters every call (graph replays don't re-poison)
  hipMemsetAsync(cnt, 0, 64, stream);

  pass1_kernel<<<NBLK, 256, 0, stream>>>(
      logits, regr, props, p_imh, p_imw, partial, rowmax);
  binsum_kernel<<<NBINS, 64, 0, stream>>>(partial, hist512);
  scan_kernel<<<1, NBINS, 0, stream>>>(hist512, cnt);
  refine_kernel<<<(NROWS + 255) / 256, 256, 0, stream>>>(
      logits, regr, props, p_imh, p_imw, rowmax, cnt, compact);
  sort_prep_kernel<<<1, 1024, 0, stream>>>(compact, cnt, regr, props, p_imh, p_imw,
                                           sel_score, sel_gidx, slabel, braw, bnms);
  iou_kernel<<<KPRE, 256, 0, stream>>>(bnms, mask);
  greedy_kernel<<<1, 256, 0, stream>>>(mask, sel_score, slabel, braw, out);
}

// Round 6
// 96.244 us; speedup vs baseline: 2.6390x; 1.1011x over previous
//
#include <hip/hip_runtime.h>
#include <cstdint>

#define NROWS 50000
#define NCLS  91
#define KPRE  1000
#define NDET  100
#define CAP   4096
#define NBINS 512
#define BIN_OFF 7680u       // bin = (bits>>17) - 7680; scores (0.05,1] -> bins [166,448]
#define LOGCLAMP 4.135166556742356f
#define ROWS_PER_BLOCK 16
#define PBLK 3126           // 3125 real blocks + 1 dummy (zero-fills pad column)
#define PB   3126           // stride (u16) per bin row in partial hist; even -> u32 reads
#define GCHUNK 128          // greedy: mask rows per LDS chunk

// ---- workspace layout (bytes) ----
constexpr size_t OFF_CNT     = 0;                      // 64 B: [0]=cutoff bin, [1]=compact count
constexpr size_t OFF_ROWMAX  = 64;                     // 50000*2 -> pad to 100096
constexpr size_t OFF_COMPACT = 100096;                 // CAP*8 = 32768
constexpr size_t OFF_SSCORE  = 132864;                 // 1024*4
constexpr size_t OFF_SGIDX   = 136960;                 // 1024*4
constexpr size_t OFF_SLABEL  = 141056;                 // 1024*4
constexpr size_t OFF_BRAW    = 145152;                 // 16384
constexpr size_t OFF_BNMS    = 161536;                 // 16384
constexpr size_t OFF_MASK    = 177920;                 // 1000*16*8 = 128000
constexpr size_t OFF_PARTIAL = 305920;                 // 512*3126*2 = 3201024
constexpr size_t OFF_HIST512 = 3506944;                // 512*4 -> end ~3.5 MB

__device__ __forceinline__ bool decode_box(int row, int c,
    const float* __restrict__ regr, const float* __restrict__ props,
    float W, float H, float4& b) {
  const float4 rr = *reinterpret_cast<const float4*>(regr + (size_t)row * (NCLS * 4) + c * 4);
  const float4 pp = *reinterpret_cast<const float4*>(props + (size_t)row * 4);
  float pw = pp.z - pp.x, ph = pp.w - pp.y;
  float cx = pp.x + 0.5f * pw, cy = pp.y + 0.5f * ph;
  float dx = rr.x / 10.0f, dy = rr.y / 10.0f;
  float dw = fminf(rr.z / 5.0f, LOGCLAMP);
  float dh = fminf(rr.w / 5.0f, LOGCLAMP);
  float pcx = dx * pw + cx, pcy = dy * ph + cy;
  float ppw = expf(dw) * pw, pph = expf(dh) * ph;
  float x1 = fminf(fmaxf(pcx - 0.5f * ppw, 0.f), W);
  float y1 = fminf(fmaxf(pcy - 0.5f * pph, 0.f), H);
  float x2 = fminf(fmaxf(pcx + 0.5f * ppw, 0.f), W);
  float y2 = fminf(fmaxf(pcy + 0.5f * pph, 0.f), H);
  b = make_float4(x1, y1, x2, y2);
  return (x2 - x1 >= 0.01f) && (y2 - y1 >= 0.01f);
}

// Pass 1: 16 threads/row, 6 classes/thread, 16 rows/block.
// LDS histogram per block; u16 partial store; NO global atomics, NO memset dep.
__global__ __launch_bounds__(256)
void pass1_kernel(const float* __restrict__ logits,
                  const float* __restrict__ regr,
                  const float* __restrict__ props,
                  const int* __restrict__ p_imh,
                  const int* __restrict__ p_imw,
                  uint16_t* __restrict__ partial,
                  uint16_t* __restrict__ rowmax) {
  __shared__ uint32_t hist[NBINS];
  const int t = threadIdx.x;
  hist[t] = 0;
  hist[t + 256] = 0;
  __syncthreads();

  const int sub = t & 15;
  const int grp = t >> 4;                        // 0..15
  const int row = blockIdx.x * ROWS_PER_BLOCK + grp;
  if (row < NROWS) {
    const float W = (float)(*p_imw), H = (float)(*p_imh);
    const float* lr = logits + (size_t)row * NCLS;
    float x[6];
    #pragma unroll
    for (int j = 0; j < 6; ++j) {
      int c = sub + 16 * j;
      x[j] = (c < NCLS) ? lr[c] : -INFINITY;
    }
    float m = x[0];
    #pragma unroll
    for (int j = 1; j < 6; ++j) m = fmaxf(m, x[j]);
    m = fmaxf(m, __shfl_xor(m, 1));
    m = fmaxf(m, __shfl_xor(m, 2));
    m = fmaxf(m, __shfl_xor(m, 4));
    m = fmaxf(m, __shfl_xor(m, 8));
    float e[6]; float s = 0.f;
    #pragma unroll
    for (int j = 0; j < 6; ++j) {
      e[j] = (sub + 16 * j < NCLS) ? expf(x[j] - m) : 0.f;
      s += e[j];
    }
    s += __shfl_xor(s, 1);
    s += __shfl_xor(s, 2);
    s += __shfl_xor(s, 4);
    s += __shfl_xor(s, 8);

    int maxbin = 0;
    #pragma unroll
    for (int j = 0; j < 6; ++j) {
      int c = sub + 16 * j;
      if (c >= 1 && c < NCLS) {
        float score = e[j] / s;
        if (score > 0.05f) {
          float4 b;
          if (decode_box(row, c, regr, props, W, H, b)) {
            uint32_t bin = (__float_as_uint(score) >> 17) - BIN_OFF;
            atomicAdd(&hist[bin], 1u);           // LDS atomic, on-CU
            if ((int)bin > maxbin) maxbin = (int)bin;
          }
        }
      }
    }
    maxbin = max(maxbin, __shfl_xor(maxbin, 1));
    maxbin = max(maxbin, __shfl_xor(maxbin, 2));
    maxbin = max(maxbin, __shfl_xor(maxbin, 4));
    maxbin = max(maxbin, __shfl_xor(maxbin, 8));
    if (sub == 0) rowmax[row] = (uint16_t)maxbin;
  }
  __syncthreads();
  // flush partial histogram: [bin][block] layout, u16 (dummy block writes zeros)
  const int blk = blockIdx.x;
  uint32_t v0 = hist[t], v1 = hist[t + 256];
  partial[(size_t)t * PB + blk]         = (uint16_t)(v0 > 65535u ? 65535u : v0);
  partial[(size_t)(t + 256) * PB + blk] = (uint16_t)(v1 > 65535u ? 65535u : v1);
}

// 512 blocks: block b sums bin b's partials (coalesced u32 reads).
__global__ __launch_bounds__(64)
void binsum_kernel(const uint16_t* __restrict__ partial, uint32_t* __restrict__ hist512) {
  const int b = blockIdx.x;
  const uint32_t* r32 = reinterpret_cast<const uint32_t*>(partial + (size_t)b * PB);
  uint32_t s = 0;
  for (int k = threadIdx.x; k < PB / 2; k += 64) {     // 1563 u32 = 3126 u16
    uint32_t v = r32[k];
    s += (v & 0xffffu) + (v >> 16);
  }
  #pragma unroll
  for (int off = 32; off; off >>= 1) s += __shfl_xor(s, off);
  if (threadIdx.x == 0) hist512[b] = s;
}

// 1 block: suffix scan of 512-bin histogram -> exact cutoff bin.
// Also zeroes the compact counter (replaces the per-call memset dispatch).
__global__ __launch_bounds__(512)
void scan_kernel(const uint32_t* __restrict__ hist512, uint32_t* __restrict__ cnt) {
  __shared__ uint32_t sh[NBINS];
  const int t = threadIdx.x;
  if (t == 0) cnt[1] = 0;                        // compact counter reset
  uint32_t s = hist512[t];
  sh[t] = s;
  __syncthreads();
  uint32_t v = s;
  for (int off = 1; off < NBINS; off <<= 1) {
    uint32_t add = (t + off < NBINS) ? sh[t + off] : 0;
    __syncthreads();
    v += add;
    sh[t] = v;
    __syncthreads();
  }
  const uint32_t total = sh[0];
  if (total == 0) { if (t == 0) cnt[0] = 0xFFFFFFFFu; return; }
  const uint32_t target = total < (uint32_t)KPRE ? total : (uint32_t)KPRE;
  const uint32_t rs_t = sh[t];
  const uint32_t rs_n = (t < NBINS - 1) ? sh[t + 1] : 0;
  if (rs_t >= target && rs_n < target) cnt[0] = (uint32_t)t;
}

// Refine: rows with rowmax >= cutoff; 4 rows per wave via 16-lane groups.
// Arithmetic replicates pass1 op-for-op (serial-6 + shfl 1,2,4,8).
__global__ __launch_bounds__(256)
void refine_kernel(const float* __restrict__ logits,
                   const float* __restrict__ regr,
                   const float* __restrict__ props,
                   const int* __restrict__ p_imh,
                   const int* __restrict__ p_imw,
                   const uint16_t* __restrict__ rowmax,
                   uint32_t* __restrict__ cnt,
                   unsigned long long* __restrict__ compact) {
  const int t = threadIdx.x;
  const int lane = t & 63;
  const int g = lane >> 4;
  const int sub = lane & 15;
  const uint32_t cut = cnt[0];
  const int myrow0 = blockIdx.x * 256 + t;
  bool qual = (myrow0 < NROWS) && ((uint32_t)rowmax[myrow0] >= cut);
  unsigned long long bm = __ballot(qual);
  if (!bm) return;
  const int waveBase = blockIdx.x * 256 + (t & ~63);
  const float W = (float)(*p_imw), H = (float)(*p_imh);

  while (bm) {
    int bsel[4];
    #pragma unroll
    for (int k = 0; k < 4; ++k) {
      bsel[k] = bm ? (__ffsll((unsigned long long)bm) - 1) : -1;
      if (bm) bm &= bm - 1;
    }
    const int myb = bsel[g];
    const int row = waveBase + (myb >= 0 ? myb : 0);
    const float* lr = logits + (size_t)row * NCLS;

    float x[6];
    #pragma unroll
    for (int j = 0; j < 6; ++j) {
      int c = sub + 16 * j;
      x[j] = (c < NCLS) ? lr[c] : -INFINITY;
    }
    float m = x[0];
    #pragma unroll
    for (int j = 1; j < 6; ++j) m = fmaxf(m, x[j]);
    m = fmaxf(m, __shfl_xor(m, 1));
    m = fmaxf(m, __shfl_xor(m, 2));
    m = fmaxf(m, __shfl_xor(m, 4));
    m = fmaxf(m, __shfl_xor(m, 8));
    float e[6]; float s = 0.f;
    #pragma unroll
    for (int j = 0; j < 6; ++j) {
      e[j] = (sub + 16 * j < NCLS) ? expf(x[j] - m) : 0.f;
      s += e[j];
    }
    s += __shfl_xor(s, 1);
    s += __shfl_xor(s, 2);
    s += __shfl_xor(s, 4);
    s += __shfl_xor(s, 8);

    if (myb >= 0) {
      #pragma unroll
      for (int j = 0; j < 6; ++j) {
        int c = sub + 16 * j;
        if (c >= 1 && c < NCLS) {
          float score = e[j] / s;
          if (score > 0.05f) {
            float4 bb;
            if (decode_box(row, c, regr, props, W, H, bb)) {
              uint32_t bits = __float_as_uint(score);
              uint32_t bin = (bits >> 17) - BIN_OFF;
              if (bin >= cut) {
                uint32_t pos = atomicAdd(&cnt[1], 1u);
                if (pos < CAP) {
                  uint32_t gidx = (uint32_t)row * 90u + (uint32_t)(c - 1);
                  compact[pos] = ((unsigned long long)bits << 32) |
                                 (unsigned long long)(0xFFFFFFFFu - gidx);
                }
              }
            }
          }
        }
      }
    }
  }
}

// Bitonic sort (width = next pow2 >= count, >=1024) + prep (decode selected).
__global__ __launch_bounds__(1024)
void sort_prep_kernel(const unsigned long long* __restrict__ compact,
                      const uint32_t* __restrict__ cnt,
                      const float* __restrict__ regr, const float* __restrict__ props,
                      const int* __restrict__ p_imh, const int* __restrict__ p_imw,
                      float* __restrict__ sel_score, uint32_t* __restrict__ sel_gidx,
                      int* __restrict__ slabel, float4* __restrict__ braw,
                      float4* __restrict__ bnms) {
  __shared__ unsigned long long arr[CAP];
  const int t = threadIdx.x;
  const uint32_t M = cnt[1] < (uint32_t)CAP ? cnt[1] : (uint32_t)CAP;
  int P = 1024;
  while (P < (int)M) P <<= 1;
  for (int i = t; i < P; i += 1024) arr[i] = (i < (int)M) ? compact[i] : 0ull;
  __syncthreads();
  for (int k = 2; k <= P; k <<= 1) {
    for (int j = k >> 1; j > 0; j >>= 1) {
      for (int i = t; i < P; i += 1024) {
        int l = i ^ j;
        if (l > i) {
          unsigned long long A = arr[i], B = arr[l];
          bool up = ((i & k) == 0);
          if (up ? (A > B) : (A < B)) { arr[i] = B; arr[l] = A; }
        }
      }
      __syncthreads();
    }
  }
  if (t < KPRE) {
    unsigned long long en = arr[P - 1 - t];   // descending
    float sc; uint32_t g;
    if (en) { sc = __uint_as_float((uint32_t)(en >> 32)); g = 0xFFFFFFFFu - (uint32_t)en; }
    else    { sc = -1.f; g = 0xFFFFFFFFu; }
    sel_score[t] = sc;
    sel_gidx[t] = g;
    if (sc > 0.f) {
      int row = (int)(g / 90u);
      int c   = (int)(g % 90u) + 1;
      float W = (float)(*p_imw), H = (float)(*p_imh);
      float4 b;
      decode_box(row, c, regr, props, W, H, b);
      braw[t] = b;
      float offv = (float)c * (float)(*p_imw + *p_imh + 2);
      bnms[t] = make_float4(b.x + offv, b.y + offv, b.z + offv, b.w + offv);
      slabel[t] = c;
    } else {
      braw[t] = make_float4(0, 0, 0, 0);
      bnms[t] = make_float4(0, 0, 0, 0);
      slabel[t] = 0;
    }
  }
}

// 256 threads/block: 4 waves x 4 mask-words each.
__global__ __launch_bounds__(256)
void iou_kernel(const float4* __restrict__ bnms, unsigned long long* __restrict__ mask) {
  const int i = blockIdx.x;
  const int lane = threadIdx.x & 63;
  const int wv = threadIdx.x >> 6;
  const float4 bi = bnms[i];
  const float areai = fmaxf(bi.z - bi.x, 0.f) * fmaxf(bi.w - bi.y, 0.f);
  #pragma unroll
  for (int ww = 0; ww < 4; ++ww) {
    int wd = wv * 4 + ww;
    int j = wd * 64 + lane;
    bool bit = false;
    if (j < KPRE && j > i) {
      float4 bj = bnms[j];
      float areaj = fmaxf(bj.z - bj.x, 0.f) * fmaxf(bj.w - bj.y, 0.f);
      float ltx = fmaxf(bi.x, bj.x), lty = fmaxf(bi.y, bj.y);
      float rbx = fminf(bi.z, bj.z), rby = fminf(bi.w, bj.w);
      float iw = fmaxf(rbx - ltx, 0.f), ih = fmaxf(rby - lty, 0.f);
      float inter = iw * ih;
      float iou = inter / (areai + areaj - inter + 1e-7f);
      bit = iou > 0.5f;
    }
    unsigned long long mword = __ballot(bit);
    if (lane == 0) mask[(size_t)i * 16 + wd] = mword;
  }
}

// Greedy NMS: wave 0 scans from LDS; waves 1-3 prefetch next mask chunk.
__global__ __launch_bounds__(256)
void greedy_kernel(const unsigned long long* __restrict__ mask,
                   const float* __restrict__ sel_score,
                   const int* __restrict__ slabel,
                   const float4* __restrict__ braw,
                   float* __restrict__ out) {
  __shared__ ulonglong2 buf[2][GCHUNK * 8];       // 2 x 16 KB
  __shared__ int kept[NDET];
  __shared__ int s_done;
  const int t = threadIdx.x;
  const int lane = t & 63;
  const int wv = t >> 6;
  const ulonglong2* gm2 = reinterpret_cast<const ulonglong2*>(mask);
  constexpr int NCHUNK = (KPRE + GCHUNK - 1) / GCHUNK;   // 8

  unsigned long long kw = 0ull;
  #pragma unroll
  for (int w = 0; w < 16; ++w) {
    int j = w * 64 + lane;
    bool b = (j < KPRE) && (sel_score[j] > 0.f);
    unsigned long long mword = __ballot(b);
    if (lane == w) kw = mword;
  }
  if (t == 0) s_done = 0;

  {
    int rows = (KPRE < GCHUNK) ? KPRE : GCHUNK;
    int n2 = rows * 8;
    for (int k = t; k < n2; k += 256) buf[0][k] = gm2[k];
  }
  __syncthreads();

  int kc = 0;
  for (int c = 0; c < NCHUNK; ++c) {
    if (wv > 0 && c + 1 < NCHUNK) {
      int rows = KPRE - (c + 1) * GCHUNK;
      if (rows > GCHUNK) rows = GCHUNK;
      int n2 = rows * 8;
      size_t gbase = (size_t)(c + 1) * GCHUNK * 8;
      for (int k = t - 64; k < n2; k += 192) buf[(c + 1) & 1][k] = gm2[gbase + k];
    }
    if (wv == 0) {
      const unsigned long long* bb =
          reinterpret_cast<const unsigned long long*>(buf[c & 1]);
      int rows = KPRE - c * GCHUNK;
      if (rows > GCHUNK) rows = GCHUNK;
      unsigned long long curm = (lane < 16) ? bb[lane] : 0ull;
      for (int r = 0; r < rows; ++r) {
        unsigned long long nxt =
            (lane < 16 && r + 1 < rows) ? bb[(r + 1) * 16 + lane] : 0ull;
        int i = c * GCHUNK + r;
        unsigned long long kwv = __shfl(kw, i >> 6);
        if ((kwv >> (i & 63)) & 1ull) {
          if (lane == 0) kept[kc] = i;
          kw &= ~curm;
          ++kc;
          if (kc >= NDET) { if (lane == 0) s_done = 1; break; }
        }
        curm = nxt;
      }
    }
    __syncthreads();
    if (s_done) break;
  }

  if (wv == 0) {
    for (int q = lane; q < NDET; q += 64) {
      if (q < kc) {
        int i = kept[q];
        float4 b = braw[i];
        out[q * 4 + 0] = b.x; out[q * 4 + 1] = b.y;
        out[q * 4 + 2] = b.z; out[q * 4 + 3] = b.w;
        out[4 * NDET + q] = sel_score[i];
        out[5 * NDET + q] = (float)slabel[i];
      } else {
        out[q * 4 + 0] = 0.f; out[q * 4 + 1] = 0.f;
        out[q * 4 + 2] = 0.f; out[q * 4 + 3] = 0.f;
        out[4 * NDET + q] = 0.f;
        out[5 * NDET + q] = 0.f;
      }
    }
  }
}

extern "C" void kernel_launch(void* const* d_in, const int* in_sizes, int n_in,
                              void* d_out, int out_size, void* d_ws, size_t ws_size,
                              hipStream_t stream) {
  const float* logits = (const float*)d_in[0];
  const float* regr   = (const float*)d_in[1];
  const float* props  = (const float*)d_in[2];
  const int*   p_imh  = (const int*)d_in[3];
  const int*   p_imw  = (const int*)d_in[4];
  float* out = (float*)d_out;

  uint8_t* ws = (uint8_t*)d_ws;
  uint32_t* cnt  = (uint32_t*)(ws + OFF_CNT);
  uint16_t* rowmax = (uint16_t*)(ws + OFF_ROWMAX);
  unsigned long long* compact = (unsigned long long*)(ws + OFF_COMPACT);
  float*    sel_score = (float*)(ws + OFF_SSCORE);
  uint32_t* sel_gidx  = (uint32_t*)(ws + OFF_SGIDX);
  int*      slabel    = (int*)(ws + OFF_SLABEL);
  float4*   braw      = (float4*)(ws + OFF_BRAW);
  float4*   bnms      = (float4*)(ws + OFF_BNMS);
  unsigned long long* mask = (unsigned long long*)(ws + OFF_MASK);
  uint16_t* partial   = (uint16_t*)(ws + OFF_PARTIAL);
  uint32_t* hist512   = (uint32_t*)(ws + OFF_HIST512);

  // NO memset dispatch: scan_kernel resets cnt[1]; cnt[0] always written by scan.

  pass1_kernel<<<PBLK, 256, 0, stream>>>(
      logits, regr, props, p_imh, p_imw, partial, rowmax);
  binsum_kernel<<<NBINS, 64, 0, stream>>>(partial, hist512);
  scan_kernel<<<1, NBINS, 0, stream>>>(hist512, cnt);
  refine_kernel<<<(NROWS + 255) / 256, 256, 0, stream>>>(
      logits, regr, props, p_imh, p_imw, rowmax, cnt, compact);
  sort_prep_kernel<<<1, 1024, 0, stream>>>(compact, cnt, regr, props, p_imh, p_imw,
                                           sel_score, sel_gidx, slabel, braw, bnms);
  iou_kernel<<<KPRE, 256, 0, stream>>>(bnms, mask);
  greedy_kernel<<<1, 256, 0, stream>>>(mask, sel_score, slabel, braw, out);
}